// Round 2
// baseline (773.068 us; speedup 1.0000x reference)
//
#include <hip/hip_runtime.h>
#include <hip/hip_bf16.h>
#include <cstdint>

#define HD   256
#define BSZ  4096
#define NFV  131072
#define NRV  262144
#define VV   8001
#define TOPKN 5

// ---------------- Threefry-2x32 (JAX-exact, 20 rounds) ----------------
__host__ __device__ __forceinline__ unsigned rotl32(unsigned v, int d) {
  return (v << d) | (v >> (32 - d));
}

__host__ __device__ __forceinline__ void threefry2x32(
    unsigned k0, unsigned k1, unsigned x0, unsigned x1,
    unsigned& o0, unsigned& o1) {
  unsigned ks2 = k0 ^ k1 ^ 0x1BD11BDAu;
  x0 += k0; x1 += k1;
  // group 1: rotations {13,15,26,6}
  x0 += x1; x1 = rotl32(x1, 13); x1 ^= x0;
  x0 += x1; x1 = rotl32(x1, 15); x1 ^= x0;
  x0 += x1; x1 = rotl32(x1, 26); x1 ^= x0;
  x0 += x1; x1 = rotl32(x1,  6); x1 ^= x0;
  x0 += k1; x1 += ks2 + 1u;
  // group 2: {17,29,16,24}
  x0 += x1; x1 = rotl32(x1, 17); x1 ^= x0;
  x0 += x1; x1 = rotl32(x1, 29); x1 ^= x0;
  x0 += x1; x1 = rotl32(x1, 16); x1 ^= x0;
  x0 += x1; x1 = rotl32(x1, 24); x1 ^= x0;
  x0 += ks2; x1 += k0 + 2u;
  // group 3
  x0 += x1; x1 = rotl32(x1, 13); x1 ^= x0;
  x0 += x1; x1 = rotl32(x1, 15); x1 ^= x0;
  x0 += x1; x1 = rotl32(x1, 26); x1 ^= x0;
  x0 += x1; x1 = rotl32(x1,  6); x1 ^= x0;
  x0 += k0; x1 += k1 + 3u;
  // group 4
  x0 += x1; x1 = rotl32(x1, 17); x1 ^= x0;
  x0 += x1; x1 = rotl32(x1, 29); x1 ^= x0;
  x0 += x1; x1 = rotl32(x1, 16); x1 ^= x0;
  x0 += x1; x1 = rotl32(x1, 24); x1 ^= x0;
  x0 += k1; x1 += ks2 + 4u;
  // group 5
  x0 += x1; x1 = rotl32(x1, 13); x1 ^= x0;
  x0 += x1; x1 = rotl32(x1, 15); x1 ^= x0;
  x0 += x1; x1 = rotl32(x1, 26); x1 ^= x0;
  x0 += x1; x1 = rotl32(x1,  6); x1 ^= x0;
  x0 += ks2; x1 += k0 + 5u;
  o0 = x0; o1 = x1;
}

// ---------------- segment fusion: node/pos/center/residue + concat ----------------
__device__ __forceinline__ int lower_bound_i(const int* __restrict__ a, int n, int v) {
  int lo = 0, hi = n;
  while (lo < hi) { int m = (lo + hi) >> 1; if (a[m] < v) lo = m + 1; else hi = m; }
  return lo;
}

__global__ __launch_bounds__(256) void fuse_seg_kernel(
    const float* __restrict__ hcf, const float* __restrict__ pcf,
    const int* __restrict__ wid, const int* __restrict__ ab,
    const float* __restrict__ hres, const float* __restrict__ rpos,
    const int* __restrict__ rb, const float* __restrict__ emb,
    float* __restrict__ pred_vecs) {
  int b = blockIdx.x, t = threadIdx.x;
  __shared__ int sa[4];
  __shared__ float sc[3];
  if (t == 0) { sa[0] = lower_bound_i(ab, NFV, b); sa[1] = lower_bound_i(ab, NFV, b + 1); }
  else if (t == 1) { sa[2] = lower_bound_i(rb, NRV, b); sa[3] = lower_bound_i(rb, NRV, b + 1); }
  __syncthreads();
  int a0 = sa[0], a1 = sa[1], r0 = sa[2], r1 = sa[3];

  float acc = 0.f;
  for (int a = a0; a < a1; ++a) acc += hcf[(size_t)a * HD + t];   // coalesced over t

  if (t < 3) {
    float p = 0.f;
    for (int a = a0; a < a1; ++a) p += pcf[(size_t)a * 3 + t];
    sc[t] = p / fmaxf((float)(a1 - a0), 1.0f);
  }
  __syncthreads();
  float cx = sc[0], cy = sc[1], cz = sc[2];

  float racc = 0.f;
  for (int r = r0; r < r1; ++r) {
    float dx = rpos[(size_t)r * 9 + 3] - cx;   // broadcast loads (same addr all lanes)
    float dy = rpos[(size_t)r * 9 + 4] - cy;
    float dz = rpos[(size_t)r * 9 + 5] - cz;
    if (sqrtf(dx * dx + dy * dy + dz * dz) < 6.0f)
      racc += hres[(size_t)r * HD + t];        // coalesced over t
  }

  size_t o = (size_t)b * (3 * HD);
  pred_vecs[o + t]          = acc;
  pred_vecs[o + HD + t]     = emb[(size_t)wid[b] * HD + t];
  pred_vecs[o + 2 * HD + t] = racc;
}

// ---------------- simple f32 tiled GEMM: C = op(A@B) (+bias)(+relu) ----------------
// A: MxK row-major. BT=false: B is KxN row-major. BT=true: B is NxK row-major.
template <bool BT, bool RELU, bool BIAS>
__global__ __launch_bounds__(256) void gemm_kernel(
    const float* __restrict__ A, const float* __restrict__ B,
    const float* __restrict__ bias, float* __restrict__ C,
    int M, int N, int K) {
  __shared__ float As[16][64];
  __shared__ float Bs[16][64];
  int t = threadIdx.x;
  int bm = blockIdx.y * 64, bn = blockIdx.x * 64;
  int tx = t & 15, ty = t >> 4;
  float acc[4][4] = {};

  for (int k0 = 0; k0 < K; k0 += 16) {
    {
      int ar = t >> 2, ak = (t & 3) << 2;   // M divisible by 64, K by 16: no guard
      float4 av = *reinterpret_cast<const float4*>(&A[(size_t)(bm + ar) * K + k0 + ak]);
      As[ak + 0][ar] = av.x; As[ak + 1][ar] = av.y;
      As[ak + 2][ar] = av.z; As[ak + 3][ar] = av.w;
    }
    if (!BT) {
      int bk = t >> 4, bnn = (t & 15) << 2;  // N=256 here: no guard
      float4 bv = *reinterpret_cast<const float4*>(&B[(size_t)(k0 + bk) * N + bn + bnn]);
      *reinterpret_cast<float4*>(&Bs[bk][bnn]) = bv;
    } else {
      int bnn = t >> 2, bk = (t & 3) << 2;
      float4 bv = make_float4(0.f, 0.f, 0.f, 0.f);
      if (bn + bnn < N)
        bv = *reinterpret_cast<const float4*>(&B[(size_t)(bn + bnn) * K + k0 + bk]);
      Bs[bk + 0][bnn] = bv.x; Bs[bk + 1][bnn] = bv.y;
      Bs[bk + 2][bnn] = bv.z; Bs[bk + 3][bnn] = bv.w;
    }
    __syncthreads();
#pragma unroll
    for (int kk = 0; kk < 16; ++kk) {
      float4 a = *reinterpret_cast<const float4*>(&As[kk][ty << 2]);
      float4 b = *reinterpret_cast<const float4*>(&Bs[kk][tx << 2]);
      float av4[4] = {a.x, a.y, a.z, a.w};
      float bv4[4] = {b.x, b.y, b.z, b.w};
#pragma unroll
      for (int i = 0; i < 4; ++i)
#pragma unroll
        for (int j = 0; j < 4; ++j)
          acc[i][j] = fmaf(av4[i], bv4[j], acc[i][j]);
    }
    __syncthreads();
  }

#pragma unroll
  for (int i = 0; i < 4; ++i) {
    int row = bm + (ty << 2) + i;
#pragma unroll
    for (int j = 0; j < 4; ++j) {
      int col = bn + (tx << 2) + j;
      if (col < N) {
        float v = acc[i][j];
        if (BIAS) v += bias[col];
        if (RELU) v = fmaxf(v, 0.f);
        C[(size_t)row * N + col] = v;
      }
    }
  }
}

// ---------------- top-5 per row (lax.top_k tie semantics) + threefry pick ----------------
// PARTITIONABLE threefry semantics (jax_threefry_partitionable=True, the
// modern default): random_bits(key,32,(n,))[i] = out0 ^ out1 of
// threefry(key, (hi=0, lo=i)).
__global__ __launch_bounds__(256) void topk_kernel(
    const float* __restrict__ scores, float* __restrict__ preds,
    unsigned k1a, unsigned k1b, unsigned k2a, unsigned k2b) {
  int lane = threadIdx.x & 63;
  int row = (blockIdx.x << 2) + (threadIdx.x >> 6);
  const float* s = scores + (size_t)row * VV;
  int sel[TOPKN];
#pragma unroll
  for (int p = 0; p < TOPKN; ++p) {
    float bv = -__builtin_huge_valf();
    int bi = 0x7FFFFFFF;
    for (int v = lane; v < VV; v += 64) {
      bool skip = false;
      for (int q = 0; q < p; ++q) skip = skip || (sel[q] == v);
      if (!skip) {
        float val = s[v];
        if (val > bv) { bv = val; bi = v; }   // strict > keeps lowest index on tie
      }
    }
#pragma unroll
    for (int off = 32; off > 0; off >>= 1) {
      float ov = __shfl_xor(bv, off);
      int   oi = __shfl_xor(bi, off);
      if (ov > bv || (ov == bv && oi < bi)) { bv = ov; bi = oi; }
    }
    sel[p] = bi;   // all lanes converge to the same winner
  }
  if (lane == 0) {
    unsigned i = (unsigned)row;
    unsigned h0, h1, l0, l1;
    threefry2x32(k1a, k1b, 0u, i, h0, h1);
    threefry2x32(k2a, k2b, 0u, i, l0, l1);
    unsigned hb = h0 ^ h1;   // 32-bit fold of the 64-bit hash
    unsigned lb = l0 ^ l1;
    unsigned idx = ((hb % 5u) + (lb % 5u)) % 5u;  // multiplier = (2^16 % 5)^2 % 5 = 1
    preds[row] = (float)sel[idx];
  }
}

extern "C" void kernel_launch(void* const* d_in, const int* in_sizes, int n_in,
                              void* d_out, int out_size, void* d_ws, size_t ws_size,
                              hipStream_t stream) {
  const float* hcf  = (const float*)d_in[0];
  const float* pcf  = (const float*)d_in[1];
  const int*   wid  = (const int*)d_in[2];
  const int*   ab   = (const int*)d_in[3];
  const float* hres = (const float*)d_in[4];
  const float* rpos = (const float*)d_in[5];
  const int*   rb   = (const int*)d_in[6];
  const float* emb  = (const float*)d_in[7];
  const float* w1   = (const float*)d_in[8];
  const float* bb1  = (const float*)d_in[9];
  const float* w2   = (const float*)d_in[10];
  const float* bb2  = (const float*)d_in[11];

  float* out    = (float*)d_out;
  float* scores = out;                             // B*V floats
  float* preds  = out + (size_t)BSZ * VV;          // B floats (indices as f32)

  // Scratch: pred_vecs and h live inside the (not-yet-written) scores region;
  // both are dead before the score GEMM overwrites them. mh must survive that
  // GEMM, so it goes in d_ws (4 MB).
  float* pred_vecs = out;                          // B*768
  float* hbuf      = out + (size_t)BSZ * 768;      // B*256
  float* mh        = (float*)d_ws;                 // B*256

  fuse_seg_kernel<<<BSZ, 256, 0, stream>>>(hcf, pcf, wid, ab, hres, rpos, rb, emb, pred_vecs);

  // h = relu(pred_vecs @ w1 + b1)
  gemm_kernel<false, true, true><<<dim3(256 / 64, BSZ / 64), 256, 0, stream>>>(
      pred_vecs, w1, bb1, hbuf, BSZ, 256, 768);
  // mh = h @ w2 + b2
  gemm_kernel<false, false, true><<<dim3(256 / 64, BSZ / 64), 256, 0, stream>>>(
      hbuf, w2, bb2, mh, BSZ, 256, 256);
  // scores = mh @ emb^T
  gemm_kernel<true, false, false><<<dim3((VV + 63) / 64, BSZ / 64), 256, 0, stream>>>(
      mh, emb, nullptr, scores, BSZ, VV, 256);

  // Host-side threefry split, PARTITIONABLE semantics:
  // split(key(1)=(0,1), 2): key_i = threefry((0,1), (hi=0, lo=i)) — both
  // output words form the new key.
  unsigned k1a, k1b, k2a, k2b;
  threefry2x32(0u, 1u, 0u, 0u, k1a, k1b);   // key1
  threefry2x32(0u, 1u, 0u, 1u, k2a, k2b);   // key2
  topk_kernel<<<BSZ / 4, 256, 0, stream>>>(scores, preds, k1a, k1b, k2a, k2b);
}

// Round 4
// 491.152 us; speedup vs baseline: 1.5740x; 1.5740x over previous
//
#include <hip/hip_runtime.h>
#include <hip/hip_bf16.h>
#include <cstdint>

#define HD   256
#define BSZ  4096
#define NFV  131072
#define NRV  262144
#define VV   8001
#define TOPKN 5

typedef __attribute__((ext_vector_type(8))) short short8v;
typedef __attribute__((ext_vector_type(4))) float float4v;

// ---------------- Threefry-2x32 (JAX-exact, 20 rounds) ----------------
__host__ __device__ __forceinline__ unsigned rotl32(unsigned v, int d) {
  return (v << d) | (v >> (32 - d));
}

__host__ __device__ __forceinline__ void threefry2x32(
    unsigned k0, unsigned k1, unsigned x0, unsigned x1,
    unsigned& o0, unsigned& o1) {
  unsigned ks2 = k0 ^ k1 ^ 0x1BD11BDAu;
  x0 += k0; x1 += k1;
  x0 += x1; x1 = rotl32(x1, 13); x1 ^= x0;
  x0 += x1; x1 = rotl32(x1, 15); x1 ^= x0;
  x0 += x1; x1 = rotl32(x1, 26); x1 ^= x0;
  x0 += x1; x1 = rotl32(x1,  6); x1 ^= x0;
  x0 += k1; x1 += ks2 + 1u;
  x0 += x1; x1 = rotl32(x1, 17); x1 ^= x0;
  x0 += x1; x1 = rotl32(x1, 29); x1 ^= x0;
  x0 += x1; x1 = rotl32(x1, 16); x1 ^= x0;
  x0 += x1; x1 = rotl32(x1, 24); x1 ^= x0;
  x0 += ks2; x1 += k0 + 2u;
  x0 += x1; x1 = rotl32(x1, 13); x1 ^= x0;
  x0 += x1; x1 = rotl32(x1, 15); x1 ^= x0;
  x0 += x1; x1 = rotl32(x1, 26); x1 ^= x0;
  x0 += x1; x1 = rotl32(x1,  6); x1 ^= x0;
  x0 += k0; x1 += k1 + 3u;
  x0 += x1; x1 = rotl32(x1, 17); x1 ^= x0;
  x0 += x1; x1 = rotl32(x1, 29); x1 ^= x0;
  x0 += x1; x1 = rotl32(x1, 16); x1 ^= x0;
  x0 += x1; x1 = rotl32(x1, 24); x1 ^= x0;
  x0 += k1; x1 += ks2 + 4u;
  x0 += x1; x1 = rotl32(x1, 13); x1 ^= x0;
  x0 += x1; x1 = rotl32(x1, 15); x1 ^= x0;
  x0 += x1; x1 = rotl32(x1, 26); x1 ^= x0;
  x0 += x1; x1 = rotl32(x1,  6); x1 ^= x0;
  x0 += ks2; x1 += k0 + 5u;
  o0 = x0; o1 = x1;
}

__device__ __forceinline__ unsigned short f2bf(float f) {
  unsigned u = __float_as_uint(f);
  unsigned r = (u + 0x7FFFu + ((u >> 16) & 1u)) >> 16;  // RNE
  return (unsigned short)r;
}
__device__ __forceinline__ float bf2f(unsigned short s) {
  return __uint_as_float(((unsigned)s) << 16);
}

// ---------------- segment fusion (unchanged, passing) ----------------
__device__ __forceinline__ int lower_bound_i(const int* __restrict__ a, int n, int v) {
  int lo = 0, hi = n;
  while (lo < hi) { int m = (lo + hi) >> 1; if (a[m] < v) lo = m + 1; else hi = m; }
  return lo;
}

__global__ __launch_bounds__(256) void fuse_seg_kernel(
    const float* __restrict__ hcf, const float* __restrict__ pcf,
    const int* __restrict__ wid, const int* __restrict__ ab,
    const float* __restrict__ hres, const float* __restrict__ rpos,
    const int* __restrict__ rb, const float* __restrict__ emb,
    float* __restrict__ pred_vecs) {
  int b = blockIdx.x, t = threadIdx.x;
  __shared__ int sa[4];
  __shared__ float sc[3];
  if (t == 0) { sa[0] = lower_bound_i(ab, NFV, b); sa[1] = lower_bound_i(ab, NFV, b + 1); }
  else if (t == 1) { sa[2] = lower_bound_i(rb, NRV, b); sa[3] = lower_bound_i(rb, NRV, b + 1); }
  __syncthreads();
  int a0 = sa[0], a1 = sa[1], r0 = sa[2], r1 = sa[3];

  float acc = 0.f;
  for (int a = a0; a < a1; ++a) acc += hcf[(size_t)a * HD + t];

  if (t < 3) {
    float p = 0.f;
    for (int a = a0; a < a1; ++a) p += pcf[(size_t)a * 3 + t];
    sc[t] = p / fmaxf((float)(a1 - a0), 1.0f);
  }
  __syncthreads();
  float cx = sc[0], cy = sc[1], cz = sc[2];

  float racc = 0.f;
  for (int r = r0; r < r1; ++r) {
    float dx = rpos[(size_t)r * 9 + 3] - cx;
    float dy = rpos[(size_t)r * 9 + 4] - cy;
    float dz = rpos[(size_t)r * 9 + 5] - cz;
    if (sqrtf(dx * dx + dy * dy + dz * dz) < 6.0f)
      racc += hres[(size_t)r * HD + t];
  }

  size_t o = (size_t)b * (3 * HD);
  pred_vecs[o + t]          = acc;
  pred_vecs[o + HD + t]     = emb[(size_t)wid[b] * HD + t];
  pred_vecs[o + 2 * HD + t] = racc;
}

// ---------------- f32 tiled GEMM for the two small MLP layers ----------------
template <bool RELU>
__global__ __launch_bounds__(256) void gemm_kernel(
    const float* __restrict__ A, const float* __restrict__ B,
    const float* __restrict__ bias, float* __restrict__ C,
    int M, int N, int K) {
  __shared__ float As[16][64];
  __shared__ float Bs[16][64];
  int t = threadIdx.x;
  int bm = blockIdx.y * 64, bn = blockIdx.x * 64;
  int tx = t & 15, ty = t >> 4;
  float acc[4][4] = {};

  for (int k0 = 0; k0 < K; k0 += 16) {
    {
      int ar = t >> 2, ak = (t & 3) << 2;
      float4 av = *reinterpret_cast<const float4*>(&A[(size_t)(bm + ar) * K + k0 + ak]);
      As[ak + 0][ar] = av.x; As[ak + 1][ar] = av.y;
      As[ak + 2][ar] = av.z; As[ak + 3][ar] = av.w;
    }
    {
      int bk = t >> 4, bnn = (t & 15) << 2;
      float4 bv = *reinterpret_cast<const float4*>(&B[(size_t)(k0 + bk) * N + bn + bnn]);
      *reinterpret_cast<float4*>(&Bs[bk][bnn]) = bv;
    }
    __syncthreads();
#pragma unroll
    for (int kk = 0; kk < 16; ++kk) {
      float4 a = *reinterpret_cast<const float4*>(&As[kk][ty << 2]);
      float4 b = *reinterpret_cast<const float4*>(&Bs[kk][tx << 2]);
      float av4[4] = {a.x, a.y, a.z, a.w};
      float bv4[4] = {b.x, b.y, b.z, b.w};
#pragma unroll
      for (int i = 0; i < 4; ++i)
#pragma unroll
        for (int j = 0; j < 4; ++j)
          acc[i][j] = fmaf(av4[i], bv4[j], acc[i][j]);
    }
    __syncthreads();
  }

#pragma unroll
  for (int i = 0; i < 4; ++i) {
    int row = bm + (ty << 2) + i;
#pragma unroll
    for (int j = 0; j < 4; ++j) {
      int col = bn + (tx << 2) + j;
      float v = acc[i][j] + bias[col];
      if (RELU) v = fmaxf(v, 0.f);
      C[(size_t)row * N + col] = v;
    }
  }
}

// ---------------- MFMA 3-term bf16-split score GEMM: C = A(f32) @ B^T(f32) ----------------
// A: M x 256 (mh). B: VV x 256 (emb, row-major = K-contiguous).
// BOTH operands split hi+lo bf16; compute aH*bH + aH*bL + aL*bH.
// Dropped aL*bL <= 2^-18 |ab| -> score error ~5e-6, same order as f32 VALU
// ordering error (which passed preds exactly in round 2).
__global__ __launch_bounds__(256) void score_gemm_kernel(
    const float* __restrict__ A, const float* __restrict__ B,
    float* __restrict__ C) {
  __shared__ unsigned short Ah[64][72];  // +8 pad: row stride 144B, 16B-aligned
  __shared__ unsigned short Al[64][72];
  __shared__ unsigned short Bh[64][72];
  __shared__ unsigned short Bl[64][72];

  int t = threadIdx.x;
  int bm = blockIdx.x * 64;          // x fastest: 64 M-blocks share one B-tile (L2)
  int bn = blockIdx.y * 64;
  int lane = t & 63, wid = t >> 6;
  int wm = wid >> 1, wn = wid & 1;   // 2x2 wave grid
  int lr = lane & 15, lg = lane >> 4;

  float4v acc[2][2];
#pragma unroll
  for (int i = 0; i < 2; ++i)
#pragma unroll
    for (int j = 0; j < 2; ++j) acc[i][j] = 0.f;

  for (int kb = 0; kb < 256; kb += 64) {
#pragma unroll
    for (int i = 0; i < 4; ++i) {
      int r = (t >> 4) + 16 * i;
      int c = (t & 15) << 2;
      float4 av = *reinterpret_cast<const float4*>(&A[(size_t)(bm + r) * 256 + kb + c]);
      float af[4] = {av.x, av.y, av.z, av.w};
      unsigned short h[4], l[4];
#pragma unroll
      for (int j = 0; j < 4; ++j) {
        h[j] = f2bf(af[j]);
        l[j] = f2bf(af[j] - bf2f(h[j]));
      }
      *reinterpret_cast<uint2*>(&Ah[r][c]) = *reinterpret_cast<uint2*>(h);
      *reinterpret_cast<uint2*>(&Al[r][c]) = *reinterpret_cast<uint2*>(l);

      int n = bn + r;
      float4 bv = make_float4(0.f, 0.f, 0.f, 0.f);
      if (n < VV)
        bv = *reinterpret_cast<const float4*>(&B[(size_t)n * 256 + kb + c]);
      float bfv[4] = {bv.x, bv.y, bv.z, bv.w};
      unsigned short bh[4], bl[4];
#pragma unroll
      for (int j = 0; j < 4; ++j) {
        bh[j] = f2bf(bfv[j]);
        bl[j] = f2bf(bfv[j] - bf2f(bh[j]));
      }
      *reinterpret_cast<uint2*>(&Bh[r][c]) = *reinterpret_cast<uint2*>(bh);
      *reinterpret_cast<uint2*>(&Bl[r][c]) = *reinterpret_cast<uint2*>(bl);
    }
    __syncthreads();

#pragma unroll
    for (int ks = 0; ks < 2; ++ks) {
      int ko = ks * 32 + lg * 8;
      short8v aH[2], aL[2], bH[2], bL[2];
#pragma unroll
      for (int mf = 0; mf < 2; ++mf) {
        aH[mf] = *reinterpret_cast<const short8v*>(&Ah[wm * 32 + mf * 16 + lr][ko]);
        aL[mf] = *reinterpret_cast<const short8v*>(&Al[wm * 32 + mf * 16 + lr][ko]);
      }
#pragma unroll
      for (int nf = 0; nf < 2; ++nf) {
        bH[nf] = *reinterpret_cast<const short8v*>(&Bh[wn * 32 + nf * 16 + lr][ko]);
        bL[nf] = *reinterpret_cast<const short8v*>(&Bl[wn * 32 + nf * 16 + lr][ko]);
      }
#pragma unroll
      for (int mf = 0; mf < 2; ++mf)
#pragma unroll
        for (int nf = 0; nf < 2; ++nf) {
          acc[mf][nf] = __builtin_amdgcn_mfma_f32_16x16x32_bf16(
              aH[mf], bH[nf], acc[mf][nf], 0, 0, 0);
          acc[mf][nf] = __builtin_amdgcn_mfma_f32_16x16x32_bf16(
              aH[mf], bL[nf], acc[mf][nf], 0, 0, 0);
          acc[mf][nf] = __builtin_amdgcn_mfma_f32_16x16x32_bf16(
              aL[mf], bH[nf], acc[mf][nf], 0, 0, 0);
        }
    }
    __syncthreads();
  }

  // epilogue: C/D layout col = lane&15, row = (lane>>4)*4 + reg  [m89]
#pragma unroll
  for (int mf = 0; mf < 2; ++mf)
#pragma unroll
    for (int nf = 0; nf < 2; ++nf) {
      int col = bn + wn * 32 + nf * 16 + lr;
      if (col < VV) {
#pragma unroll
        for (int r = 0; r < 4; ++r) {
          int row = bm + wm * 32 + mf * 16 + lg * 4 + r;
          C[(size_t)row * VV + col] = acc[mf][nf][r];
        }
      }
    }
}

// ---------------- single-pass top-5 + threefry pick ----------------
#define BETTER(av, ai, bv, bi) ((av) > (bv) || ((av) == (bv) && (ai) < (bi)))

__global__ __launch_bounds__(256) void topk_kernel(
    const float* __restrict__ scores, float* __restrict__ preds,
    unsigned k1a, unsigned k1b, unsigned k2a, unsigned k2b) {
  int lane = threadIdx.x & 63;
  int row = (blockIdx.x << 2) + (threadIdx.x >> 6);
  const float* s = scores + (size_t)row * VV;

  const float NEG = -__builtin_huge_valf();
  float v0 = NEG, v1 = NEG, v2 = NEG, v3 = NEG, v4 = NEG;
  int i0 = 0x7FFFFFFF, i1 = 0x7FFFFFFF, i2 = 0x7FFFFFFF, i3 = 0x7FFFFFFF, i4 = 0x7FFFFFFF;

  for (int v = lane; v < VV; v += 64) {
    float val = s[v];
    if (BETTER(val, v, v4, i4)) {
      if (BETTER(val, v, v3, i3)) {
        v4 = v3; i4 = i3;
        if (BETTER(val, v, v2, i2)) {
          v3 = v2; i3 = i2;
          if (BETTER(val, v, v1, i1)) {
            v2 = v1; i2 = i1;
            if (BETTER(val, v, v0, i0)) {
              v1 = v0; i1 = i0; v0 = val; i0 = v;
            } else { v1 = val; i1 = v; }
          } else { v2 = val; i2 = v; }
        } else { v3 = val; i3 = v; }
      } else { v4 = val; i4 = v; }
    }
  }

  int sel0, sel1, sel2, sel3, sel4;
#pragma unroll
  for (int p = 0; p < TOPKN; ++p) {
    float bv = v0; int bi = i0;
#pragma unroll
    for (int off = 32; off > 0; off >>= 1) {
      float ov = __shfl_xor(bv, off);
      int   oi = __shfl_xor(bi, off);
      if (BETTER(ov, oi, bv, bi)) { bv = ov; bi = oi; }
    }
    if (p == 0) sel0 = bi; else if (p == 1) sel1 = bi; else if (p == 2) sel2 = bi;
    else if (p == 3) sel3 = bi; else sel4 = bi;
    if (bi == i0) {  // owner lane removes its head
      v0 = v1; i0 = i1; v1 = v2; i1 = i2; v2 = v3; i2 = i3; v3 = v4; i3 = i4;
      v4 = NEG; i4 = 0x7FFFFFFF;
    }
  }

  if (lane == 0) {
    unsigned i = (unsigned)row;
    unsigned h0, h1, l0, l1;
    threefry2x32(k1a, k1b, 0u, i, h0, h1);
    threefry2x32(k2a, k2b, 0u, i, l0, l1);
    unsigned hb = h0 ^ h1;
    unsigned lb = l0 ^ l1;
    unsigned idx = ((hb % 5u) + (lb % 5u)) % 5u;
    int pick = (idx == 0) ? sel0 : (idx == 1) ? sel1 : (idx == 2) ? sel2
             : (idx == 3) ? sel3 : sel4;
    preds[row] = (float)pick;
  }
}

extern "C" void kernel_launch(void* const* d_in, const int* in_sizes, int n_in,
                              void* d_out, int out_size, void* d_ws, size_t ws_size,
                              hipStream_t stream) {
  const float* hcf  = (const float*)d_in[0];
  const float* pcf  = (const float*)d_in[1];
  const int*   wid  = (const int*)d_in[2];
  const int*   ab   = (const int*)d_in[3];
  const float* hres = (const float*)d_in[4];
  const float* rpos = (const float*)d_in[5];
  const int*   rb   = (const int*)d_in[6];
  const float* emb  = (const float*)d_in[7];
  const float* w1   = (const float*)d_in[8];
  const float* bb1  = (const float*)d_in[9];
  const float* w2   = (const float*)d_in[10];
  const float* bb2  = (const float*)d_in[11];

  float* out    = (float*)d_out;
  float* scores = out;
  float* preds  = out + (size_t)BSZ * VV;

  float* pred_vecs = out;                          // dead before scores written
  float* hbuf      = out + (size_t)BSZ * 768;      // dead before scores written
  float* mh        = (float*)d_ws;                 // survives score GEMM

  fuse_seg_kernel<<<BSZ, 256, 0, stream>>>(hcf, pcf, wid, ab, hres, rpos, rb, emb, pred_vecs);

  gemm_kernel<true><<<dim3(256 / 64, BSZ / 64), 256, 0, stream>>>(
      pred_vecs, w1, bb1, hbuf, BSZ, 256, 768);
  gemm_kernel<false><<<dim3(256 / 64, BSZ / 64), 256, 0, stream>>>(
      hbuf, w2, bb2, mh, BSZ, 256, 256);

  score_gemm_kernel<<<dim3(BSZ / 64, (VV + 63) / 64), 256, 0, stream>>>(mh, emb, scores);

  unsigned k1a, k1b, k2a, k2b;
  threefry2x32(0u, 1u, 0u, 0u, k1a, k1b);
  threefry2x32(0u, 1u, 0u, 1u, k2a, k2b);
  topk_kernel<<<BSZ / 4, 256, 0, stream>>>(scores, preds, k1a, k1b, k2a, k2b);
}

// Round 5
// 406.579 us; speedup vs baseline: 1.9014x; 1.2080x over previous
//
#include <hip/hip_runtime.h>
#include <hip/hip_bf16.h>
#include <cstdint>

#define HD   256
#define BSZ  4096
#define NFV  131072
#define NRV  262144
#define VV   8001
#define TOPKN 5

typedef __attribute__((ext_vector_type(8))) short short8v;
typedef __attribute__((ext_vector_type(4))) float float4v;

// ---------------- Threefry-2x32 (JAX-exact, 20 rounds) ----------------
__host__ __device__ __forceinline__ unsigned rotl32(unsigned v, int d) {
  return (v << d) | (v >> (32 - d));
}

__host__ __device__ __forceinline__ void threefry2x32(
    unsigned k0, unsigned k1, unsigned x0, unsigned x1,
    unsigned& o0, unsigned& o1) {
  unsigned ks2 = k0 ^ k1 ^ 0x1BD11BDAu;
  x0 += k0; x1 += k1;
  x0 += x1; x1 = rotl32(x1, 13); x1 ^= x0;
  x0 += x1; x1 = rotl32(x1, 15); x1 ^= x0;
  x0 += x1; x1 = rotl32(x1, 26); x1 ^= x0;
  x0 += x1; x1 = rotl32(x1,  6); x1 ^= x0;
  x0 += k1; x1 += ks2 + 1u;
  x0 += x1; x1 = rotl32(x1, 17); x1 ^= x0;
  x0 += x1; x1 = rotl32(x1, 29); x1 ^= x0;
  x0 += x1; x1 = rotl32(x1, 16); x1 ^= x0;
  x0 += x1; x1 = rotl32(x1, 24); x1 ^= x0;
  x0 += ks2; x1 += k0 + 2u;
  x0 += x1; x1 = rotl32(x1, 13); x1 ^= x0;
  x0 += x1; x1 = rotl32(x1, 15); x1 ^= x0;
  x0 += x1; x1 = rotl32(x1, 26); x1 ^= x0;
  x0 += x1; x1 = rotl32(x1,  6); x1 ^= x0;
  x0 += k0; x1 += k1 + 3u;
  x0 += x1; x1 = rotl32(x1, 17); x1 ^= x0;
  x0 += x1; x1 = rotl32(x1, 29); x1 ^= x0;
  x0 += x1; x1 = rotl32(x1, 16); x1 ^= x0;
  x0 += x1; x1 = rotl32(x1, 24); x1 ^= x0;
  x0 += k1; x1 += ks2 + 4u;
  x0 += x1; x1 = rotl32(x1, 13); x1 ^= x0;
  x0 += x1; x1 = rotl32(x1, 15); x1 ^= x0;
  x0 += x1; x1 = rotl32(x1, 26); x1 ^= x0;
  x0 += x1; x1 = rotl32(x1,  6); x1 ^= x0;
  x0 += ks2; x1 += k0 + 5u;
  o0 = x0; o1 = x1;
}

__device__ __forceinline__ unsigned short f2bf(float f) {
  unsigned u = __float_as_uint(f);
  unsigned r = (u + 0x7FFFu + ((u >> 16) & 1u)) >> 16;  // RNE
  return (unsigned short)r;
}
__device__ __forceinline__ float bf2f(unsigned short s) {
  return __uint_as_float(((unsigned)s) << 16);
}

// ---------------- segment fusion: wave-parallel rows + float4 loads ----------------
__device__ __forceinline__ int lower_bound_i(const int* __restrict__ a, int n, int v) {
  int lo = 0, hi = n;
  while (lo < hi) { int m = (lo + hi) >> 1; if (a[m] < v) lo = m + 1; else hi = m; }
  return lo;
}

__global__ __launch_bounds__(256) void fuse_seg_kernel(
    const float* __restrict__ hcf, const float* __restrict__ pcf,
    const int* __restrict__ wid, const int* __restrict__ ab,
    const float* __restrict__ hres, const float* __restrict__ rpos,
    const int* __restrict__ rb, const float* __restrict__ emb,
    float* __restrict__ pred_vecs) {
  int b = blockIdx.x, t = threadIdx.x;
  int lane = t & 63, w = t >> 6;
  __shared__ int sa[4];
  __shared__ float sc[3];
  __shared__ float4v red[4][64];
  if (t == 0) { sa[0] = lower_bound_i(ab, NFV, b); sa[1] = lower_bound_i(ab, NFV, b + 1); }
  else if (t == 1) { sa[2] = lower_bound_i(rb, NRV, b); sa[3] = lower_bound_i(rb, NRV, b + 1); }
  __syncthreads();
  int a0 = sa[0], a1 = sa[1], r0 = sa[2], r1 = sa[3];

  // node sum: wave w owns rows a0+w, a0+w+4, ... ; lane owns dims [4*lane..4*lane+3]
  float4v acc = 0.f;
  for (int a = a0 + w; a < a1; a += 4)
    acc += *reinterpret_cast<const float4v*>(&hcf[(size_t)a * HD + lane * 4]);
  red[w][lane] = acc;

  // center: BIT-IDENTICAL to the passing serial version (mask boundary safety)
  if (t < 3) {
    float p = 0.f;
    for (int a = a0; a < a1; ++a) p += pcf[(size_t)a * 3 + t];
    sc[t] = p / fmaxf((float)(a1 - a0), 1.0f);
  }
  __syncthreads();
  float cx = sc[0], cy = sc[1], cz = sc[2];

  size_t o = (size_t)b * (3 * HD);
  if (w == 0) {
    float4v s = red[0][lane] + red[1][lane] + red[2][lane] + red[3][lane];
    *reinterpret_cast<float4v*>(&pred_vecs[o + lane * 4]) = s;
  } else if (w == 1) {
    float4v m = *reinterpret_cast<const float4v*>(&emb[(size_t)wid[b] * HD + lane * 4]);
    *reinterpret_cast<float4v*>(&pred_vecs[o + HD + lane * 4]) = m;
  }

  // residue sum: unconditional row load (mask ~always true), predicated add
  float4v racc = 0.f;
  for (int r = r0 + w; r < r1; r += 4) {
    float4v v = *reinterpret_cast<const float4v*>(&hres[(size_t)r * HD + lane * 4]);
    float dx = rpos[(size_t)r * 9 + 3] - cx;
    float dy = rpos[(size_t)r * 9 + 4] - cy;
    float dz = rpos[(size_t)r * 9 + 5] - cz;
    if (dx * dx + dy * dy + dz * dz < 36.0f)   // == sqrtf(d2) < 6.0f exactly
      racc += v;
  }
  __syncthreads();            // red last read above by wave 0
  red[w][lane] = racc;
  __syncthreads();
  if (w == 0) {
    float4v s = red[0][lane] + red[1][lane] + red[2][lane] + red[3][lane];
    *reinterpret_cast<float4v*>(&pred_vecs[o + 2 * HD + lane * 4]) = s;
  }
}

// ---------------- f32 tiled GEMM for the two small MLP layers ----------------
template <bool RELU>
__global__ __launch_bounds__(256) void gemm_kernel(
    const float* __restrict__ A, const float* __restrict__ B,
    const float* __restrict__ bias, float* __restrict__ C,
    int M, int N, int K) {
  __shared__ float As[16][64];
  __shared__ float Bs[16][64];
  int t = threadIdx.x;
  int bm = blockIdx.y * 64, bn = blockIdx.x * 64;
  int tx = t & 15, ty = t >> 4;
  float acc[4][4] = {};

  for (int k0 = 0; k0 < K; k0 += 16) {
    {
      int ar = t >> 2, ak = (t & 3) << 2;
      float4 av = *reinterpret_cast<const float4*>(&A[(size_t)(bm + ar) * K + k0 + ak]);
      As[ak + 0][ar] = av.x; As[ak + 1][ar] = av.y;
      As[ak + 2][ar] = av.z; As[ak + 3][ar] = av.w;
    }
    {
      int bk = t >> 4, bnn = (t & 15) << 2;
      float4 bv = *reinterpret_cast<const float4*>(&B[(size_t)(k0 + bk) * N + bn + bnn]);
      *reinterpret_cast<float4*>(&Bs[bk][bnn]) = bv;
    }
    __syncthreads();
#pragma unroll
    for (int kk = 0; kk < 16; ++kk) {
      float4 a = *reinterpret_cast<const float4*>(&As[kk][ty << 2]);
      float4 b = *reinterpret_cast<const float4*>(&Bs[kk][tx << 2]);
      float av4[4] = {a.x, a.y, a.z, a.w};
      float bv4[4] = {b.x, b.y, b.z, b.w};
#pragma unroll
      for (int i = 0; i < 4; ++i)
#pragma unroll
        for (int j = 0; j < 4; ++j)
          acc[i][j] = fmaf(av4[i], bv4[j], acc[i][j]);
    }
    __syncthreads();
  }

#pragma unroll
  for (int i = 0; i < 4; ++i) {
    int row = bm + (ty << 2) + i;
#pragma unroll
    for (int j = 0; j < 4; ++j) {
      int col = bn + (tx << 2) + j;
      float v = acc[i][j] + bias[col];
      if (RELU) v = fmaxf(v, 0.f);
      C[(size_t)row * N + col] = v;
    }
  }
}

// ---------------- MFMA 3-term bf16-split score GEMM: C = A(f32) @ B^T(f32) ----------------
__global__ __launch_bounds__(256) void score_gemm_kernel(
    const float* __restrict__ A, const float* __restrict__ B,
    float* __restrict__ C) {
  __shared__ unsigned short Ah[64][72];  // +8 pad: row stride 144B, 16B-aligned
  __shared__ unsigned short Al[64][72];
  __shared__ unsigned short Bh[64][72];
  __shared__ unsigned short Bl[64][72];

  int t = threadIdx.x;
  int bm = blockIdx.x * 64;          // x fastest: 64 M-blocks share one B-tile (L2)
  int bn = blockIdx.y * 64;
  int lane = t & 63, wid = t >> 6;
  int wm = wid >> 1, wn = wid & 1;   // 2x2 wave grid
  int lr = lane & 15, lg = lane >> 4;

  float4v acc[2][2];
#pragma unroll
  for (int i = 0; i < 2; ++i)
#pragma unroll
    for (int j = 0; j < 2; ++j) acc[i][j] = 0.f;

  for (int kb = 0; kb < 256; kb += 64) {
#pragma unroll
    for (int i = 0; i < 4; ++i) {
      int r = (t >> 4) + 16 * i;
      int c = (t & 15) << 2;
      float4 av = *reinterpret_cast<const float4*>(&A[(size_t)(bm + r) * 256 + kb + c]);
      float af[4] = {av.x, av.y, av.z, av.w};
      unsigned short h[4], l[4];
#pragma unroll
      for (int j = 0; j < 4; ++j) {
        h[j] = f2bf(af[j]);
        l[j] = f2bf(af[j] - bf2f(h[j]));
      }
      *reinterpret_cast<uint2*>(&Ah[r][c]) = *reinterpret_cast<uint2*>(h);
      *reinterpret_cast<uint2*>(&Al[r][c]) = *reinterpret_cast<uint2*>(l);

      int n = bn + r;
      float4 bv = make_float4(0.f, 0.f, 0.f, 0.f);
      if (n < VV)
        bv = *reinterpret_cast<const float4*>(&B[(size_t)n * 256 + kb + c]);
      float bfv[4] = {bv.x, bv.y, bv.z, bv.w};
      unsigned short bh[4], bl[4];
#pragma unroll
      for (int j = 0; j < 4; ++j) {
        bh[j] = f2bf(bfv[j]);
        bl[j] = f2bf(bfv[j] - bf2f(bh[j]));
      }
      *reinterpret_cast<uint2*>(&Bh[r][c]) = *reinterpret_cast<uint2*>(bh);
      *reinterpret_cast<uint2*>(&Bl[r][c]) = *reinterpret_cast<uint2*>(bl);
    }
    __syncthreads();

#pragma unroll
    for (int ks = 0; ks < 2; ++ks) {
      int ko = ks * 32 + lg * 8;
      short8v aH[2], aL[2], bH[2], bL[2];
#pragma unroll
      for (int mf = 0; mf < 2; ++mf) {
        aH[mf] = *reinterpret_cast<const short8v*>(&Ah[wm * 32 + mf * 16 + lr][ko]);
        aL[mf] = *reinterpret_cast<const short8v*>(&Al[wm * 32 + mf * 16 + lr][ko]);
      }
#pragma unroll
      for (int nf = 0; nf < 2; ++nf) {
        bH[nf] = *reinterpret_cast<const short8v*>(&Bh[wn * 32 + nf * 16 + lr][ko]);
        bL[nf] = *reinterpret_cast<const short8v*>(&Bl[wn * 32 + nf * 16 + lr][ko]);
      }
#pragma unroll
      for (int mf = 0; mf < 2; ++mf)
#pragma unroll
        for (int nf = 0; nf < 2; ++nf) {
          acc[mf][nf] = __builtin_amdgcn_mfma_f32_16x16x32_bf16(
              aH[mf], bH[nf], acc[mf][nf], 0, 0, 0);
          acc[mf][nf] = __builtin_amdgcn_mfma_f32_16x16x32_bf16(
              aH[mf], bL[nf], acc[mf][nf], 0, 0, 0);
          acc[mf][nf] = __builtin_amdgcn_mfma_f32_16x16x32_bf16(
              aL[mf], bH[nf], acc[mf][nf], 0, 0, 0);
        }
    }
    __syncthreads();
  }

  // epilogue: C/D layout col = lane&15, row = (lane>>4)*4 + reg  [m89]
#pragma unroll
  for (int mf = 0; mf < 2; ++mf)
#pragma unroll
    for (int nf = 0; nf < 2; ++nf) {
      int col = bn + wn * 32 + nf * 16 + lr;
      if (col < VV) {
#pragma unroll
        for (int r = 0; r < 4; ++r) {
          int row = bm + wm * 32 + mf * 16 + lg * 4 + r;
          C[(size_t)row * VV + col] = acc[mf][nf][r];
        }
      }
    }
}

// ---------------- single-pass top-5 + threefry pick ----------------
#define BETTER(av, ai, bv, bi) ((av) > (bv) || ((av) == (bv) && (ai) < (bi)))

__global__ __launch_bounds__(256) void topk_kernel(
    const float* __restrict__ scores, float* __restrict__ preds,
    unsigned k1a, unsigned k1b, unsigned k2a, unsigned k2b) {
  int lane = threadIdx.x & 63;
  int row = (blockIdx.x << 2) + (threadIdx.x >> 6);
  const float* s = scores + (size_t)row * VV;

  const float NEG = -__builtin_huge_valf();
  float v0 = NEG, v1 = NEG, v2 = NEG, v3 = NEG, v4 = NEG;
  int i0 = 0x7FFFFFFF, i1 = 0x7FFFFFFF, i2 = 0x7FFFFFFF, i3 = 0x7FFFFFFF, i4 = 0x7FFFFFFF;

  for (int v = lane; v < VV; v += 64) {
    float val = s[v];
    if (BETTER(val, v, v4, i4)) {
      if (BETTER(val, v, v3, i3)) {
        v4 = v3; i4 = i3;
        if (BETTER(val, v, v2, i2)) {
          v3 = v2; i3 = i2;
          if (BETTER(val, v, v1, i1)) {
            v2 = v1; i2 = i1;
            if (BETTER(val, v, v0, i0)) {
              v1 = v0; i1 = i0; v0 = val; i0 = v;
            } else { v1 = val; i1 = v; }
          } else { v2 = val; i2 = v; }
        } else { v3 = val; i3 = v; }
      } else { v4 = val; i4 = v; }
    }
  }

  int sel0, sel1, sel2, sel3, sel4;
#pragma unroll
  for (int p = 0; p < TOPKN; ++p) {
    float bv = v0; int bi = i0;
#pragma unroll
    for (int off = 32; off > 0; off >>= 1) {
      float ov = __shfl_xor(bv, off);
      int   oi = __shfl_xor(bi, off);
      if (BETTER(ov, oi, bv, bi)) { bv = ov; bi = oi; }
    }
    if (p == 0) sel0 = bi; else if (p == 1) sel1 = bi; else if (p == 2) sel2 = bi;
    else if (p == 3) sel3 = bi; else sel4 = bi;
    if (bi == i0) {  // owner lane removes its head
      v0 = v1; i0 = i1; v1 = v2; i1 = i2; v2 = v3; i2 = i3; v3 = v4; i3 = i4;
      v4 = NEG; i4 = 0x7FFFFFFF;
    }
  }

  if (lane == 0) {
    unsigned i = (unsigned)row;
    unsigned h0, h1, l0, l1;
    threefry2x32(k1a, k1b, 0u, i, h0, h1);
    threefry2x32(k2a, k2b, 0u, i, l0, l1);
    unsigned hb = h0 ^ h1;
    unsigned lb = l0 ^ l1;
    unsigned idx = ((hb % 5u) + (lb % 5u)) % 5u;
    int pick = (idx == 0) ? sel0 : (idx == 1) ? sel1 : (idx == 2) ? sel2
             : (idx == 3) ? sel3 : sel4;
    preds[row] = (float)pick;
  }
}

extern "C" void kernel_launch(void* const* d_in, const int* in_sizes, int n_in,
                              void* d_out, int out_size, void* d_ws, size_t ws_size,
                              hipStream_t stream) {
  const float* hcf  = (const float*)d_in[0];
  const float* pcf  = (const float*)d_in[1];
  const int*   wid  = (const int*)d_in[2];
  const int*   ab   = (const int*)d_in[3];
  const float* hres = (const float*)d_in[4];
  const float* rpos = (const float*)d_in[5];
  const int*   rb   = (const int*)d_in[6];
  const float* emb  = (const float*)d_in[7];
  const float* w1   = (const float*)d_in[8];
  const float* bb1  = (const float*)d_in[9];
  const float* w2   = (const float*)d_in[10];
  const float* bb2  = (const float*)d_in[11];

  float* out    = (float*)d_out;
  float* scores = out;
  float* preds  = out + (size_t)BSZ * VV;

  float* pred_vecs = out;                          // dead before scores written
  float* hbuf      = out + (size_t)BSZ * 768;      // dead before scores written
  float* mh        = (float*)d_ws;                 // survives score GEMM

  fuse_seg_kernel<<<BSZ, 256, 0, stream>>>(hcf, pcf, wid, ab, hres, rpos, rb, emb, pred_vecs);

  gemm_kernel<true><<<dim3(256 / 64, BSZ / 64), 256, 0, stream>>>(
      pred_vecs, w1, bb1, hbuf, BSZ, 256, 768);
  gemm_kernel<false><<<dim3(256 / 64, BSZ / 64), 256, 0, stream>>>(
      hbuf, w2, bb2, mh, BSZ, 256, 256);

  score_gemm_kernel<<<dim3(BSZ / 64, (VV + 63) / 64), 256, 0, stream>>>(mh, emb, scores);

  unsigned k1a, k1b, k2a, k2b;
  threefry2x32(0u, 1u, 0u, 0u, k1a, k1b);
  threefry2x32(0u, 1u, 0u, 1u, k2a, k2b);
  topk_kernel<<<BSZ / 4, 256, 0, stream>>>(scores, preds, k1a, k1b, k2a, k2b);
}

// Round 6
// 403.739 us; speedup vs baseline: 1.9148x; 1.0070x over previous
//
#include <hip/hip_runtime.h>
#include <hip/hip_bf16.h>
#include <cstdint>

#define HD   256
#define BSZ  4096
#define NFV  131072
#define NRV  262144
#define VV   8001
#define TOPKN 5
#define RBOFF (BSZ + 1)

typedef __attribute__((ext_vector_type(8))) short short8v;
typedef __attribute__((ext_vector_type(4))) float float4v;

// ---------------- Threefry-2x32 (JAX-exact, 20 rounds) ----------------
__host__ __device__ __forceinline__ unsigned rotl32(unsigned v, int d) {
  return (v << d) | (v >> (32 - d));
}

__host__ __device__ __forceinline__ void threefry2x32(
    unsigned k0, unsigned k1, unsigned x0, unsigned x1,
    unsigned& o0, unsigned& o1) {
  unsigned ks2 = k0 ^ k1 ^ 0x1BD11BDAu;
  x0 += k0; x1 += k1;
  x0 += x1; x1 = rotl32(x1, 13); x1 ^= x0;
  x0 += x1; x1 = rotl32(x1, 15); x1 ^= x0;
  x0 += x1; x1 = rotl32(x1, 26); x1 ^= x0;
  x0 += x1; x1 = rotl32(x1,  6); x1 ^= x0;
  x0 += k1; x1 += ks2 + 1u;
  x0 += x1; x1 = rotl32(x1, 17); x1 ^= x0;
  x0 += x1; x1 = rotl32(x1, 29); x1 ^= x0;
  x0 += x1; x1 = rotl32(x1, 16); x1 ^= x0;
  x0 += x1; x1 = rotl32(x1, 24); x1 ^= x0;
  x0 += ks2; x1 += k0 + 2u;
  x0 += x1; x1 = rotl32(x1, 13); x1 ^= x0;
  x0 += x1; x1 = rotl32(x1, 15); x1 ^= x0;
  x0 += x1; x1 = rotl32(x1, 26); x1 ^= x0;
  x0 += x1; x1 = rotl32(x1,  6); x1 ^= x0;
  x0 += k0; x1 += k1 + 3u;
  x0 += x1; x1 = rotl32(x1, 17); x1 ^= x0;
  x0 += x1; x1 = rotl32(x1, 29); x1 ^= x0;
  x0 += x1; x1 = rotl32(x1, 16); x1 ^= x0;
  x0 += x1; x1 = rotl32(x1, 24); x1 ^= x0;
  x0 += k1; x1 += ks2 + 4u;
  x0 += x1; x1 = rotl32(x1, 13); x1 ^= x0;
  x0 += x1; x1 = rotl32(x1, 15); x1 ^= x0;
  x0 += x1; x1 = rotl32(x1, 26); x1 ^= x0;
  x0 += x1; x1 = rotl32(x1,  6); x1 ^= x0;
  x0 += ks2; x1 += k0 + 5u;
  o0 = x0; o1 = x1;
}

__device__ __forceinline__ unsigned short f2bf(float f) {
  unsigned u = __float_as_uint(f);
  unsigned r = (u + 0x7FFFu + ((u >> 16) & 1u)) >> 16;  // RNE
  return (unsigned short)r;
}
__device__ __forceinline__ float bf2f(unsigned short s) {
  return __uint_as_float(((unsigned)s) << 16);
}

__device__ __forceinline__ int lower_bound_i(const int* __restrict__ a, int n, int v) {
  int lo = 0, hi = n;
  while (lo < hi) { int m = (lo + hi) >> 1; if (a[m] < v) lo = m + 1; else hi = m; }
  return lo;
}

// ---------------- parallel segment-bounds precompute ----------------
__global__ __launch_bounds__(256) void seg_bounds_kernel(
    const int* __restrict__ ab, const int* __restrict__ rb,
    int* __restrict__ bounds) {
  int i = blockIdx.x * 256 + threadIdx.x;
  if (i <= BSZ) bounds[i] = lower_bound_i(ab, NFV, i);
  else if (i <= 2 * BSZ + 1) bounds[i] = lower_bound_i(rb, NRV, i - RBOFF);
}

// ---------------- segment fusion: one wave per batch element, no barriers ----------------
__global__ __launch_bounds__(256) void fuse_seg_kernel(
    const float* __restrict__ hcf, const float* __restrict__ pcf,
    const int* __restrict__ wid,
    const float* __restrict__ hres, const float* __restrict__ rpos,
    const float* __restrict__ emb, const int* __restrict__ bounds,
    float* __restrict__ pred_vecs) {
  int lane = threadIdx.x & 63;
  int b = blockIdx.x * 4 + (threadIdx.x >> 6);
  int a0 = bounds[b], a1 = bounds[b + 1];
  int r0 = bounds[RBOFF + b], r1 = bounds[RBOFF + b + 1];

  // node sum: lane owns dims [4*lane..4*lane+3]; 2-deep pipelined
  float4v acc = 0.f;
  if (a0 < a1) {
    float4v nv = *reinterpret_cast<const float4v*>(&hcf[(size_t)a0 * HD + lane * 4]);
    for (int a = a0; a < a1; ++a) {
      float4v cv = nv;
      if (a + 1 < a1)
        nv = *reinterpret_cast<const float4v*>(&hcf[(size_t)(a + 1) * HD + lane * 4]);
      acc += cv;
    }
  }

  // center: bit-identical serial ascending order (mask-boundary safety), 3 lanes
  float cp = 0.f;
  if (lane < 3 && a0 < a1) {
    float nv = pcf[(size_t)a0 * 3 + lane];
    for (int a = a0; a < a1; ++a) {
      float cv = nv;
      if (a + 1 < a1) nv = pcf[(size_t)(a + 1) * 3 + lane];
      cp += cv;
    }
  }
  if (lane < 3) cp = cp / fmaxf((float)(a1 - a0), 1.0f);
  float cx = __shfl(cp, 0), cy = __shfl(cp, 1), cz = __shfl(cp, 2);

  size_t o = (size_t)b * (3 * HD);
  *reinterpret_cast<float4v*>(&pred_vecs[o + lane * 4]) = acc;
  float4v mv = *reinterpret_cast<const float4v*>(&emb[(size_t)wid[b] * HD + lane * 4]);
  *reinterpret_cast<float4v*>(&pred_vecs[o + HD + lane * 4]) = mv;

  // residue sum: unconditional row load, predicated add, 2-deep pipelined
  float4v racc = 0.f;
  if (r0 < r1) {
    float4v nv = *reinterpret_cast<const float4v*>(&hres[(size_t)r0 * HD + lane * 4]);
    float nx = rpos[(size_t)r0 * 9 + 3];
    float ny = rpos[(size_t)r0 * 9 + 4];
    float nz = rpos[(size_t)r0 * 9 + 5];
    for (int r = r0; r < r1; ++r) {
      float4v cv = nv;
      float px = nx, py = ny, pz = nz;
      if (r + 1 < r1) {
        size_t rn = (size_t)(r + 1);
        nv = *reinterpret_cast<const float4v*>(&hres[rn * HD + lane * 4]);
        nx = rpos[rn * 9 + 3]; ny = rpos[rn * 9 + 4]; nz = rpos[rn * 9 + 5];
      }
      float dx = px - cx, dy = py - cy, dz = pz - cz;
      if (dx * dx + dy * dy + dz * dz < 36.0f)   // == sqrtf(d2) < 6.0f exactly
        racc += cv;
    }
  }
  *reinterpret_cast<float4v*>(&pred_vecs[o + 2 * HD + lane * 4]) = racc;
}

// ---------------- f32 tiled GEMM for the two small MLP layers ----------------
template <bool RELU>
__global__ __launch_bounds__(256) void gemm_kernel(
    const float* __restrict__ A, const float* __restrict__ B,
    const float* __restrict__ bias, float* __restrict__ C,
    int M, int N, int K) {
  __shared__ float As[16][64];
  __shared__ float Bs[16][64];
  int t = threadIdx.x;
  int bm = blockIdx.y * 64, bn = blockIdx.x * 64;
  int tx = t & 15, ty = t >> 4;
  float acc[4][4] = {};

  for (int k0 = 0; k0 < K; k0 += 16) {
    {
      int ar = t >> 2, ak = (t & 3) << 2;
      float4 av = *reinterpret_cast<const float4*>(&A[(size_t)(bm + ar) * K + k0 + ak]);
      As[ak + 0][ar] = av.x; As[ak + 1][ar] = av.y;
      As[ak + 2][ar] = av.z; As[ak + 3][ar] = av.w;
    }
    {
      int bk = t >> 4, bnn = (t & 15) << 2;
      float4 bv = *reinterpret_cast<const float4*>(&B[(size_t)(k0 + bk) * N + bn + bnn]);
      *reinterpret_cast<float4*>(&Bs[bk][bnn]) = bv;
    }
    __syncthreads();
#pragma unroll
    for (int kk = 0; kk < 16; ++kk) {
      float4 a = *reinterpret_cast<const float4*>(&As[kk][ty << 2]);
      float4 b = *reinterpret_cast<const float4*>(&Bs[kk][tx << 2]);
      float av4[4] = {a.x, a.y, a.z, a.w};
      float bv4[4] = {b.x, b.y, b.z, b.w};
#pragma unroll
      for (int i = 0; i < 4; ++i)
#pragma unroll
        for (int j = 0; j < 4; ++j)
          acc[i][j] = fmaf(av4[i], bv4[j], acc[i][j]);
    }
    __syncthreads();
  }

#pragma unroll
  for (int i = 0; i < 4; ++i) {
    int row = bm + (ty << 2) + i;
#pragma unroll
    for (int j = 0; j < 4; ++j) {
      int col = bn + (tx << 2) + j;
      float v = acc[i][j] + bias[col];
      if (RELU) v = fmaxf(v, 0.f);
      C[(size_t)row * N + col] = v;
    }
  }
}

// ---------------- MFMA 3-term bf16-split score GEMM: C = A(f32) @ B^T(f32) ----------------
__global__ __launch_bounds__(256) void score_gemm_kernel(
    const float* __restrict__ A, const float* __restrict__ B,
    float* __restrict__ C) {
  __shared__ unsigned short Ah[64][72];  // +8 pad: row stride 144B, 16B-aligned
  __shared__ unsigned short Al[64][72];
  __shared__ unsigned short Bh[64][72];
  __shared__ unsigned short Bl[64][72];

  int t = threadIdx.x;
  int bm = blockIdx.x * 64;          // x fastest: 64 M-blocks share one B-tile (L2)
  int bn = blockIdx.y * 64;
  int lane = t & 63, wid = t >> 6;
  int wm = wid >> 1, wn = wid & 1;   // 2x2 wave grid
  int lr = lane & 15, lg = lane >> 4;

  float4v acc[2][2];
#pragma unroll
  for (int i = 0; i < 2; ++i)
#pragma unroll
    for (int j = 0; j < 2; ++j) acc[i][j] = 0.f;

  for (int kb = 0; kb < 256; kb += 64) {
#pragma unroll
    for (int i = 0; i < 4; ++i) {
      int r = (t >> 4) + 16 * i;
      int c = (t & 15) << 2;
      float4 av = *reinterpret_cast<const float4*>(&A[(size_t)(bm + r) * 256 + kb + c]);
      float af[4] = {av.x, av.y, av.z, av.w};
      unsigned short h[4], l[4];
#pragma unroll
      for (int j = 0; j < 4; ++j) {
        h[j] = f2bf(af[j]);
        l[j] = f2bf(af[j] - bf2f(h[j]));
      }
      *reinterpret_cast<uint2*>(&Ah[r][c]) = *reinterpret_cast<uint2*>(h);
      *reinterpret_cast<uint2*>(&Al[r][c]) = *reinterpret_cast<uint2*>(l);

      int n = bn + r;
      float4 bv = make_float4(0.f, 0.f, 0.f, 0.f);
      if (n < VV)
        bv = *reinterpret_cast<const float4*>(&B[(size_t)n * 256 + kb + c]);
      float bfv[4] = {bv.x, bv.y, bv.z, bv.w};
      unsigned short bh[4], bl[4];
#pragma unroll
      for (int j = 0; j < 4; ++j) {
        bh[j] = f2bf(bfv[j]);
        bl[j] = f2bf(bfv[j] - bf2f(bh[j]));
      }
      *reinterpret_cast<uint2*>(&Bh[r][c]) = *reinterpret_cast<uint2*>(bh);
      *reinterpret_cast<uint2*>(&Bl[r][c]) = *reinterpret_cast<uint2*>(bl);
    }
    __syncthreads();

#pragma unroll
    for (int ks = 0; ks < 2; ++ks) {
      int ko = ks * 32 + lg * 8;
      short8v aH[2], aL[2], bH[2], bL[2];
#pragma unroll
      for (int mf = 0; mf < 2; ++mf) {
        aH[mf] = *reinterpret_cast<const short8v*>(&Ah[wm * 32 + mf * 16 + lr][ko]);
        aL[mf] = *reinterpret_cast<const short8v*>(&Al[wm * 32 + mf * 16 + lr][ko]);
      }
#pragma unroll
      for (int nf = 0; nf < 2; ++nf) {
        bH[nf] = *reinterpret_cast<const short8v*>(&Bh[wn * 32 + nf * 16 + lr][ko]);
        bL[nf] = *reinterpret_cast<const short8v*>(&Bl[wn * 32 + nf * 16 + lr][ko]);
      }
#pragma unroll
      for (int mf = 0; mf < 2; ++mf)
#pragma unroll
        for (int nf = 0; nf < 2; ++nf) {
          acc[mf][nf] = __builtin_amdgcn_mfma_f32_16x16x32_bf16(
              aH[mf], bH[nf], acc[mf][nf], 0, 0, 0);
          acc[mf][nf] = __builtin_amdgcn_mfma_f32_16x16x32_bf16(
              aH[mf], bL[nf], acc[mf][nf], 0, 0, 0);
          acc[mf][nf] = __builtin_amdgcn_mfma_f32_16x16x32_bf16(
              aL[mf], bH[nf], acc[mf][nf], 0, 0, 0);
        }
    }
    __syncthreads();
  }

  // epilogue: C/D layout col = lane&15, row = (lane>>4)*4 + reg  [m89]
#pragma unroll
  for (int mf = 0; mf < 2; ++mf)
#pragma unroll
    for (int nf = 0; nf < 2; ++nf) {
      int col = bn + wn * 32 + nf * 16 + lr;
      if (col < VV) {
#pragma unroll
        for (int r = 0; r < 4; ++r) {
          int row = bm + wm * 32 + mf * 16 + lg * 4 + r;
          C[(size_t)row * VV + col] = acc[mf][nf][r];
        }
      }
    }
}

// ---------------- single-pass top-5 + threefry pick ----------------
#define BETTER(av, ai, bv, bi) ((av) > (bv) || ((av) == (bv) && (ai) < (bi)))

__global__ __launch_bounds__(256) void topk_kernel(
    const float* __restrict__ scores, float* __restrict__ preds,
    unsigned k1a, unsigned k1b, unsigned k2a, unsigned k2b) {
  int lane = threadIdx.x & 63;
  int row = (blockIdx.x << 2) + (threadIdx.x >> 6);
  const float* s = scores + (size_t)row * VV;

  const float NEG = -__builtin_huge_valf();
  float v0 = NEG, v1 = NEG, v2 = NEG, v3 = NEG, v4 = NEG;
  int i0 = 0x7FFFFFFF, i1 = 0x7FFFFFFF, i2 = 0x7FFFFFFF, i3 = 0x7FFFFFFF, i4 = 0x7FFFFFFF;

  for (int v = lane; v < VV; v += 64) {
    float val = s[v];
    if (BETTER(val, v, v4, i4)) {
      if (BETTER(val, v, v3, i3)) {
        v4 = v3; i4 = i3;
        if (BETTER(val, v, v2, i2)) {
          v3 = v2; i3 = i2;
          if (BETTER(val, v, v1, i1)) {
            v2 = v1; i2 = i1;
            if (BETTER(val, v, v0, i0)) {
              v1 = v0; i1 = i0; v0 = val; i0 = v;
            } else { v1 = val; i1 = v; }
          } else { v2 = val; i2 = v; }
        } else { v3 = val; i3 = v; }
      } else { v4 = val; i4 = v; }
    }
  }

  int sel0, sel1, sel2, sel3, sel4;
#pragma unroll
  for (int p = 0; p < TOPKN; ++p) {
    float bv = v0; int bi = i0;
#pragma unroll
    for (int off = 32; off > 0; off >>= 1) {
      float ov = __shfl_xor(bv, off);
      int   oi = __shfl_xor(bi, off);
      if (BETTER(ov, oi, bv, bi)) { bv = ov; bi = oi; }
    }
    if (p == 0) sel0 = bi; else if (p == 1) sel1 = bi; else if (p == 2) sel2 = bi;
    else if (p == 3) sel3 = bi; else sel4 = bi;
    if (bi == i0) {  // owner lane removes its head
      v0 = v1; i0 = i1; v1 = v2; i1 = i2; v2 = v3; i2 = i3; v3 = v4; i3 = i4;
      v4 = NEG; i4 = 0x7FFFFFFF;
    }
  }

  if (lane == 0) {
    unsigned i = (unsigned)row;
    unsigned h0, h1, l0, l1;
    threefry2x32(k1a, k1b, 0u, i, h0, h1);
    threefry2x32(k2a, k2b, 0u, i, l0, l1);
    unsigned hb = h0 ^ h1;
    unsigned lb = l0 ^ l1;
    unsigned idx = ((hb % 5u) + (lb % 5u)) % 5u;
    int pick = (idx == 0) ? sel0 : (idx == 1) ? sel1 : (idx == 2) ? sel2
             : (idx == 3) ? sel3 : sel4;
    preds[row] = (float)pick;
  }
}

extern "C" void kernel_launch(void* const* d_in, const int* in_sizes, int n_in,
                              void* d_out, int out_size, void* d_ws, size_t ws_size,
                              hipStream_t stream) {
  const float* hcf  = (const float*)d_in[0];
  const float* pcf  = (const float*)d_in[1];
  const int*   wid  = (const int*)d_in[2];
  const int*   ab   = (const int*)d_in[3];
  const float* hres = (const float*)d_in[4];
  const float* rpos = (const float*)d_in[5];
  const int*   rb   = (const int*)d_in[6];
  const float* emb  = (const float*)d_in[7];
  const float* w1   = (const float*)d_in[8];
  const float* bb1  = (const float*)d_in[9];
  const float* w2   = (const float*)d_in[10];
  const float* bb2  = (const float*)d_in[11];

  float* out    = (float*)d_out;
  float* scores = out;
  float* preds  = out + (size_t)BSZ * VV;

  float* pred_vecs = out;                          // dead before scores written
  float* hbuf      = out + (size_t)BSZ * 768;      // dead before scores written
  float* mh        = (float*)d_ws;                 // survives score GEMM
  int*   bounds    = (int*)d_ws;                   // 32 KB; dead before mh written

  seg_bounds_kernel<<<(2 * (BSZ + 1) + 255) / 256, 256, 0, stream>>>(ab, rb, bounds);

  fuse_seg_kernel<<<BSZ / 4, 256, 0, stream>>>(
      hcf, pcf, wid, hres, rpos, emb, bounds, pred_vecs);

  gemm_kernel<true><<<dim3(256 / 64, BSZ / 64), 256, 0, stream>>>(
      pred_vecs, w1, bb1, hbuf, BSZ, 256, 768);
  gemm_kernel<false><<<dim3(256 / 64, BSZ / 64), 256, 0, stream>>>(
      hbuf, w2, bb2, mh, BSZ, 256, 256);

  score_gemm_kernel<<<dim3(BSZ / 64, (VV + 63) / 64), 256, 0, stream>>>(mh, emb, scores);

  unsigned k1a, k1b, k2a, k2b;
  threefry2x32(0u, 1u, 0u, 0u, k1a, k1b);
  threefry2x32(0u, 1u, 0u, 1u, k2a, k2b);
  topk_kernel<<<BSZ / 4, 256, 0, stream>>>(scores, preds, k1a, k1b, k2a, k2b);
}

// Round 7
// 383.799 us; speedup vs baseline: 2.0143x; 1.0520x over previous
//
#include <hip/hip_runtime.h>
#include <hip/hip_bf16.h>
#include <cstdint>

#define HD   256
#define BSZ  4096
#define NFV  131072
#define NRV  262144
#define VV   8001
#define TOPKN 5
#define RBOFF (BSZ + 1)

typedef __attribute__((ext_vector_type(8))) short short8v;
typedef __attribute__((ext_vector_type(4))) float float4v;

// ---------------- Threefry-2x32 (JAX-exact, 20 rounds) ----------------
__host__ __device__ __forceinline__ unsigned rotl32(unsigned v, int d) {
  return (v << d) | (v >> (32 - d));
}

__host__ __device__ __forceinline__ void threefry2x32(
    unsigned k0, unsigned k1, unsigned x0, unsigned x1,
    unsigned& o0, unsigned& o1) {
  unsigned ks2 = k0 ^ k1 ^ 0x1BD11BDAu;
  x0 += k0; x1 += k1;
  x0 += x1; x1 = rotl32(x1, 13); x1 ^= x0;
  x0 += x1; x1 = rotl32(x1, 15); x1 ^= x0;
  x0 += x1; x1 = rotl32(x1, 26); x1 ^= x0;
  x0 += x1; x1 = rotl32(x1,  6); x1 ^= x0;
  x0 += k1; x1 += ks2 + 1u;
  x0 += x1; x1 = rotl32(x1, 17); x1 ^= x0;
  x0 += x1; x1 = rotl32(x1, 29); x1 ^= x0;
  x0 += x1; x1 = rotl32(x1, 16); x1 ^= x0;
  x0 += x1; x1 = rotl32(x1, 24); x1 ^= x0;
  x0 += ks2; x1 += k0 + 2u;
  x0 += x1; x1 = rotl32(x1, 13); x1 ^= x0;
  x0 += x1; x1 = rotl32(x1, 15); x1 ^= x0;
  x0 += x1; x1 = rotl32(x1, 26); x1 ^= x0;
  x0 += x1; x1 = rotl32(x1,  6); x1 ^= x0;
  x0 += k0; x1 += k1 + 3u;
  x0 += x1; x1 = rotl32(x1, 17); x1 ^= x0;
  x0 += x1; x1 = rotl32(x1, 29); x1 ^= x0;
  x0 += x1; x1 = rotl32(x1, 16); x1 ^= x0;
  x0 += x1; x1 = rotl32(x1, 24); x1 ^= x0;
  x0 += k1; x1 += ks2 + 4u;
  x0 += x1; x1 = rotl32(x1, 13); x1 ^= x0;
  x0 += x1; x1 = rotl32(x1, 15); x1 ^= x0;
  x0 += x1; x1 = rotl32(x1, 26); x1 ^= x0;
  x0 += x1; x1 = rotl32(x1,  6); x1 ^= x0;
  x0 += ks2; x1 += k0 + 5u;
  o0 = x0; o1 = x1;
}

__device__ __forceinline__ unsigned short f2bf(float f) {
  unsigned u = __float_as_uint(f);
  unsigned r = (u + 0x7FFFu + ((u >> 16) & 1u)) >> 16;  // RNE
  return (unsigned short)r;
}
__device__ __forceinline__ float bf2f(unsigned short s) {
  return __uint_as_float(((unsigned)s) << 16);
}

__device__ __forceinline__ int lower_bound_i(const int* __restrict__ a, int n, int v) {
  int lo = 0, hi = n;
  while (lo < hi) { int m = (lo + hi) >> 1; if (a[m] < v) lo = m + 1; else hi = m; }
  return lo;
}

// ---------------- parallel segment-bounds precompute ----------------
__global__ __launch_bounds__(256) void seg_bounds_kernel(
    const int* __restrict__ ab, const int* __restrict__ rb,
    int* __restrict__ bounds) {
  int i = blockIdx.x * 256 + threadIdx.x;
  if (i <= BSZ) bounds[i] = lower_bound_i(ab, NFV, i);
  else if (i <= 2 * BSZ + 1) bounds[i] = lower_bound_i(rb, NRV, i - RBOFF);
}

// ---------------- segment fusion: one wave per element, 8-row MLP chunks ----------------
__global__ __launch_bounds__(256) void fuse_seg_kernel(
    const float* __restrict__ hcf, const float* __restrict__ pcf,
    const int* __restrict__ wid,
    const float* __restrict__ hres, const float* __restrict__ rpos,
    const float* __restrict__ emb, const int* __restrict__ bounds,
    float* __restrict__ pred_vecs) {
  int lane = threadIdx.x & 63;
  int b = blockIdx.x * 4 + (threadIdx.x >> 6);
  int a0 = bounds[b], a1 = bounds[b + 1];
  int r0 = bounds[RBOFF + b], r1 = bounds[RBOFF + b + 1];
  size_t off = (size_t)lane * 4;

  // node sum: 8 independent row loads in flight per chunk (MLP, not 1-ahead)
  float4v acc = 0.f;
  int a = a0;
  for (; a + 8 <= a1; a += 8) {
    float4v v[8];
#pragma unroll
    for (int j = 0; j < 8; ++j)
      v[j] = *reinterpret_cast<const float4v*>(&hcf[(size_t)(a + j) * HD + off]);
    acc += ((v[0] + v[1]) + (v[2] + v[3])) + ((v[4] + v[5]) + (v[6] + v[7]));
  }
  for (; a < a1; ++a)
    acc += *reinterpret_cast<const float4v*>(&hcf[(size_t)a * HD + off]);

  // center: bit-identical serial ascending order (mask-boundary safety), 3 lanes
  float cp = 0.f;
  if (lane < 3 && a0 < a1) {
    float nv = pcf[(size_t)a0 * 3 + lane];
    for (int aa = a0; aa < a1; ++aa) {
      float cv = nv;
      if (aa + 1 < a1) nv = pcf[(size_t)(aa + 1) * 3 + lane];
      cp += cv;
    }
  }
  if (lane < 3) cp = cp / fmaxf((float)(a1 - a0), 1.0f);
  float cx = __shfl(cp, 0), cy = __shfl(cp, 1), cz = __shfl(cp, 2);

  size_t o = (size_t)b * (3 * HD);
  *reinterpret_cast<float4v*>(&pred_vecs[o + off]) = acc;
  float4v mv = *reinterpret_cast<const float4v*>(&emb[(size_t)wid[b] * HD + off]);
  *reinterpret_cast<float4v*>(&pred_vecs[o + HD + off]) = mv;

  // residue sum: 8-row chunks, select-then-add (== where(mask,h,0) semantics)
  float4v racc = 0.f;
  int r = r0;
  for (; r + 8 <= r1; r += 8) {
    float4v v[8];
    float d2[8];
#pragma unroll
    for (int j = 0; j < 8; ++j) {
      size_t rr = (size_t)(r + j);
      v[j] = *reinterpret_cast<const float4v*>(&hres[rr * HD + off]);
      float dx = rpos[rr * 9 + 3] - cx;
      float dy = rpos[rr * 9 + 4] - cy;
      float dz = rpos[rr * 9 + 5] - cz;
      d2[j] = dx * dx + dy * dy + dz * dz;
    }
    float4v s0 = 0.f, s1 = 0.f, s2 = 0.f, s3 = 0.f;
#pragma unroll
    for (int j = 0; j < 8; j += 4) {
      if (d2[j + 0] < 36.0f) s0 += v[j + 0];
      if (d2[j + 1] < 36.0f) s1 += v[j + 1];
      if (d2[j + 2] < 36.0f) s2 += v[j + 2];
      if (d2[j + 3] < 36.0f) s3 += v[j + 3];
    }
    racc += (s0 + s1) + (s2 + s3);
  }
  for (; r < r1; ++r) {
    float4v v = *reinterpret_cast<const float4v*>(&hres[(size_t)r * HD + off]);
    float dx = rpos[(size_t)r * 9 + 3] - cx;
    float dy = rpos[(size_t)r * 9 + 4] - cy;
    float dz = rpos[(size_t)r * 9 + 5] - cz;
    if (dx * dx + dy * dy + dz * dz < 36.0f)
      racc += v;
  }
  *reinterpret_cast<float4v*>(&pred_vecs[o + 2 * HD + off]) = racc;
}

// ---------------- f32 tiled GEMM for the two small MLP layers ----------------
template <bool RELU>
__global__ __launch_bounds__(256) void gemm_kernel(
    const float* __restrict__ A, const float* __restrict__ B,
    const float* __restrict__ bias, float* __restrict__ C,
    int M, int N, int K) {
  __shared__ float As[16][64];
  __shared__ float Bs[16][64];
  int t = threadIdx.x;
  int bm = blockIdx.y * 64, bn = blockIdx.x * 64;
  int tx = t & 15, ty = t >> 4;
  float acc[4][4] = {};

  for (int k0 = 0; k0 < K; k0 += 16) {
    {
      int ar = t >> 2, ak = (t & 3) << 2;
      float4 av = *reinterpret_cast<const float4*>(&A[(size_t)(bm + ar) * K + k0 + ak]);
      As[ak + 0][ar] = av.x; As[ak + 1][ar] = av.y;
      As[ak + 2][ar] = av.z; As[ak + 3][ar] = av.w;
    }
    {
      int bk = t >> 4, bnn = (t & 15) << 2;
      float4 bv = *reinterpret_cast<const float4*>(&B[(size_t)(k0 + bk) * N + bn + bnn]);
      *reinterpret_cast<float4*>(&Bs[bk][bnn]) = bv;
    }
    __syncthreads();
#pragma unroll
    for (int kk = 0; kk < 16; ++kk) {
      float4 a = *reinterpret_cast<const float4*>(&As[kk][ty << 2]);
      float4 b = *reinterpret_cast<const float4*>(&Bs[kk][tx << 2]);
      float av4[4] = {a.x, a.y, a.z, a.w};
      float bv4[4] = {b.x, b.y, b.z, b.w};
#pragma unroll
      for (int i = 0; i < 4; ++i)
#pragma unroll
        for (int j = 0; j < 4; ++j)
          acc[i][j] = fmaf(av4[i], bv4[j], acc[i][j]);
    }
    __syncthreads();
  }

#pragma unroll
  for (int i = 0; i < 4; ++i) {
    int row = bm + (ty << 2) + i;
#pragma unroll
    for (int j = 0; j < 4; ++j) {
      int col = bn + (tx << 2) + j;
      float v = acc[i][j] + bias[col];
      if (RELU) v = fmaxf(v, 0.f);
      C[(size_t)row * N + col] = v;
    }
  }
}

// ---------------- MFMA 3-term bf16-split score GEMM: C = A(f32) @ B^T(f32) ----------------
__global__ __launch_bounds__(256) void score_gemm_kernel(
    const float* __restrict__ A, const float* __restrict__ B,
    float* __restrict__ C) {
  __shared__ unsigned short Ah[64][72];  // +8 pad: row stride 144B, 16B-aligned
  __shared__ unsigned short Al[64][72];
  __shared__ unsigned short Bh[64][72];
  __shared__ unsigned short Bl[64][72];

  int t = threadIdx.x;
  int bm = blockIdx.x * 64;          // x fastest: 64 M-blocks share one B-tile (L2)
  int bn = blockIdx.y * 64;
  int lane = t & 63, wid = t >> 6;
  int wm = wid >> 1, wn = wid & 1;   // 2x2 wave grid
  int lr = lane & 15, lg = lane >> 4;

  float4v acc[2][2];
#pragma unroll
  for (int i = 0; i < 2; ++i)
#pragma unroll
    for (int j = 0; j < 2; ++j) acc[i][j] = 0.f;

  for (int kb = 0; kb < 256; kb += 64) {
#pragma unroll
    for (int i = 0; i < 4; ++i) {
      int r = (t >> 4) + 16 * i;
      int c = (t & 15) << 2;
      float4 av = *reinterpret_cast<const float4*>(&A[(size_t)(bm + r) * 256 + kb + c]);
      float af[4] = {av.x, av.y, av.z, av.w};
      unsigned short h[4], l[4];
#pragma unroll
      for (int j = 0; j < 4; ++j) {
        h[j] = f2bf(af[j]);
        l[j] = f2bf(af[j] - bf2f(h[j]));
      }
      *reinterpret_cast<uint2*>(&Ah[r][c]) = *reinterpret_cast<uint2*>(h);
      *reinterpret_cast<uint2*>(&Al[r][c]) = *reinterpret_cast<uint2*>(l);

      int n = bn + r;
      float4 bv = make_float4(0.f, 0.f, 0.f, 0.f);
      if (n < VV)
        bv = *reinterpret_cast<const float4*>(&B[(size_t)n * 256 + kb + c]);
      float bfv[4] = {bv.x, bv.y, bv.z, bv.w};
      unsigned short bh[4], bl[4];
#pragma unroll
      for (int j = 0; j < 4; ++j) {
        bh[j] = f2bf(bfv[j]);
        bl[j] = f2bf(bfv[j] - bf2f(bh[j]));
      }
      *reinterpret_cast<uint2*>(&Bh[r][c]) = *reinterpret_cast<uint2*>(bh);
      *reinterpret_cast<uint2*>(&Bl[r][c]) = *reinterpret_cast<uint2*>(bl);
    }
    __syncthreads();

#pragma unroll
    for (int ks = 0; ks < 2; ++ks) {
      int ko = ks * 32 + lg * 8;
      short8v aH[2], aL[2], bH[2], bL[2];
#pragma unroll
      for (int mf = 0; mf < 2; ++mf) {
        aH[mf] = *reinterpret_cast<const short8v*>(&Ah[wm * 32 + mf * 16 + lr][ko]);
        aL[mf] = *reinterpret_cast<const short8v*>(&Al[wm * 32 + mf * 16 + lr][ko]);
      }
#pragma unroll
      for (int nf = 0; nf < 2; ++nf) {
        bH[nf] = *reinterpret_cast<const short8v*>(&Bh[wn * 32 + nf * 16 + lr][ko]);
        bL[nf] = *reinterpret_cast<const short8v*>(&Bl[wn * 32 + nf * 16 + lr][ko]);
      }
#pragma unroll
      for (int mf = 0; mf < 2; ++mf)
#pragma unroll
        for (int nf = 0; nf < 2; ++nf) {
          acc[mf][nf] = __builtin_amdgcn_mfma_f32_16x16x32_bf16(
              aH[mf], bH[nf], acc[mf][nf], 0, 0, 0);
          acc[mf][nf] = __builtin_amdgcn_mfma_f32_16x16x32_bf16(
              aH[mf], bL[nf], acc[mf][nf], 0, 0, 0);
          acc[mf][nf] = __builtin_amdgcn_mfma_f32_16x16x32_bf16(
              aL[mf], bH[nf], acc[mf][nf], 0, 0, 0);
        }
    }
    __syncthreads();
  }

  // epilogue: C/D layout col = lane&15, row = (lane>>4)*4 + reg  [m89]
#pragma unroll
  for (int mf = 0; mf < 2; ++mf)
#pragma unroll
    for (int nf = 0; nf < 2; ++nf) {
      int col = bn + wn * 32 + nf * 16 + lr;
      if (col < VV) {
#pragma unroll
        for (int r = 0; r < 4; ++r) {
          int row = bm + wm * 32 + mf * 16 + lg * 4 + r;
          C[(size_t)row * VV + col] = acc[mf][nf][r];
        }
      }
    }
}

// ---------------- single-pass top-5 + threefry pick ----------------
#define BETTER(av, ai, bv, bi) ((av) > (bv) || ((av) == (bv) && (ai) < (bi)))

__global__ __launch_bounds__(256) void topk_kernel(
    const float* __restrict__ scores, float* __restrict__ preds,
    unsigned k1a, unsigned k1b, unsigned k2a, unsigned k2b) {
  int lane = threadIdx.x & 63;
  int row = (blockIdx.x << 2) + (threadIdx.x >> 6);
  const float* s = scores + (size_t)row * VV;

  const float NEG = -__builtin_huge_valf();
  float v0 = NEG, v1 = NEG, v2 = NEG, v3 = NEG, v4 = NEG;
  int i0 = 0x7FFFFFFF, i1 = 0x7FFFFFFF, i2 = 0x7FFFFFFF, i3 = 0x7FFFFFFF, i4 = 0x7FFFFFFF;

  for (int v = lane; v < VV; v += 64) {
    float val = s[v];
    if (BETTER(val, v, v4, i4)) {
      if (BETTER(val, v, v3, i3)) {
        v4 = v3; i4 = i3;
        if (BETTER(val, v, v2, i2)) {
          v3 = v2; i3 = i2;
          if (BETTER(val, v, v1, i1)) {
            v2 = v1; i2 = i1;
            if (BETTER(val, v, v0, i0)) {
              v1 = v0; i1 = i0; v0 = val; i0 = v;
            } else { v1 = val; i1 = v; }
          } else { v2 = val; i2 = v; }
        } else { v3 = val; i3 = v; }
      } else { v4 = val; i4 = v; }
    }
  }

  int sel0, sel1, sel2, sel3, sel4;
#pragma unroll
  for (int p = 0; p < TOPKN; ++p) {
    float bv = v0; int bi = i0;
#pragma unroll
    for (int off = 32; off > 0; off >>= 1) {
      float ov = __shfl_xor(bv, off);
      int   oi = __shfl_xor(bi, off);
      if (BETTER(ov, oi, bv, bi)) { bv = ov; bi = oi; }
    }
    if (p == 0) sel0 = bi; else if (p == 1) sel1 = bi; else if (p == 2) sel2 = bi;
    else if (p == 3) sel3 = bi; else sel4 = bi;
    if (bi == i0) {  // owner lane removes its head
      v0 = v1; i0 = i1; v1 = v2; i1 = i2; v2 = v3; i2 = i3; v3 = v4; i3 = i4;
      v4 = NEG; i4 = 0x7FFFFFFF;
    }
  }

  if (lane == 0) {
    unsigned i = (unsigned)row;
    unsigned h0, h1, l0, l1;
    threefry2x32(k1a, k1b, 0u, i, h0, h1);
    threefry2x32(k2a, k2b, 0u, i, l0, l1);
    unsigned hb = h0 ^ h1;
    unsigned lb = l0 ^ l1;
    unsigned idx = ((hb % 5u) + (lb % 5u)) % 5u;
    int pick = (idx == 0) ? sel0 : (idx == 1) ? sel1 : (idx == 2) ? sel2
             : (idx == 3) ? sel3 : sel4;
    preds[row] = (float)pick;
  }
}

extern "C" void kernel_launch(void* const* d_in, const int* in_sizes, int n_in,
                              void* d_out, int out_size, void* d_ws, size_t ws_size,
                              hipStream_t stream) {
  const float* hcf  = (const float*)d_in[0];
  const float* pcf  = (const float*)d_in[1];
  const int*   wid  = (const int*)d_in[2];
  const int*   ab   = (const int*)d_in[3];
  const float* hres = (const float*)d_in[4];
  const float* rpos = (const float*)d_in[5];
  const int*   rb   = (const int*)d_in[6];
  const float* emb  = (const float*)d_in[7];
  const float* w1   = (const float*)d_in[8];
  const float* bb1  = (const float*)d_in[9];
  const float* w2   = (const float*)d_in[10];
  const float* bb2  = (const float*)d_in[11];

  float* out    = (float*)d_out;
  float* scores = out;
  float* preds  = out + (size_t)BSZ * VV;

  float* pred_vecs = out;                          // dead before scores written
  float* hbuf      = out + (size_t)BSZ * 768;      // dead before scores written
  float* mh        = (float*)d_ws;                 // survives score GEMM
  int*   bounds    = (int*)d_ws;                   // 32 KB; dead before mh written

  seg_bounds_kernel<<<(2 * (BSZ + 1) + 255) / 256, 256, 0, stream>>>(ab, rb, bounds);

  fuse_seg_kernel<<<BSZ / 4, 256, 0, stream>>>(
      hcf, pcf, wid, hres, rpos, emb, bounds, pred_vecs);

  gemm_kernel<true><<<dim3(256 / 64, BSZ / 64), 256, 0, stream>>>(
      pred_vecs, w1, bb1, hbuf, BSZ, 256, 768);
  gemm_kernel<false><<<dim3(256 / 64, BSZ / 64), 256, 0, stream>>>(
      hbuf, w2, bb2, mh, BSZ, 256, 256);

  score_gemm_kernel<<<dim3(BSZ / 64, (VV + 63) / 64), 256, 0, stream>>>(mh, emb, scores);

  unsigned k1a, k1b, k2a, k2b;
  threefry2x32(0u, 1u, 0u, 0u, k1a, k1b);
  threefry2x32(0u, 1u, 0u, 1u, k2a, k2b);
  topk_kernel<<<BSZ / 4, 256, 0, stream>>>(scores, preds, k1a, k1b, k2a, k2b);
}

// Round 8
// 344.575 us; speedup vs baseline: 2.2435x; 1.1138x over previous
//
#include <hip/hip_runtime.h>
#include <hip/hip_bf16.h>
#include <cstdint>

#define HD   256
#define BSZ  4096
#define NFV  131072
#define NRV  262144
#define VV   8001
#define TOPKN 5
#define RBOFF (BSZ + 1)
#define EPAD 8064   // emb rows padded to 63*128

typedef __attribute__((ext_vector_type(8))) short short8v;
typedef __attribute__((ext_vector_type(4))) float float4v;

// ---------------- Threefry-2x32 (JAX-exact, 20 rounds) ----------------
__host__ __device__ __forceinline__ unsigned rotl32(unsigned v, int d) {
  return (v << d) | (v >> (32 - d));
}

__host__ __device__ __forceinline__ void threefry2x32(
    unsigned k0, unsigned k1, unsigned x0, unsigned x1,
    unsigned& o0, unsigned& o1) {
  unsigned ks2 = k0 ^ k1 ^ 0x1BD11BDAu;
  x0 += k0; x1 += k1;
  x0 += x1; x1 = rotl32(x1, 13); x1 ^= x0;
  x0 += x1; x1 = rotl32(x1, 15); x1 ^= x0;
  x0 += x1; x1 = rotl32(x1, 26); x1 ^= x0;
  x0 += x1; x1 = rotl32(x1,  6); x1 ^= x0;
  x0 += k1; x1 += ks2 + 1u;
  x0 += x1; x1 = rotl32(x1, 17); x1 ^= x0;
  x0 += x1; x1 = rotl32(x1, 29); x1 ^= x0;
  x0 += x1; x1 = rotl32(x1, 16); x1 ^= x0;
  x0 += x1; x1 = rotl32(x1, 24); x1 ^= x0;
  x0 += ks2; x1 += k0 + 2u;
  x0 += x1; x1 = rotl32(x1, 13); x1 ^= x0;
  x0 += x1; x1 = rotl32(x1, 15); x1 ^= x0;
  x0 += x1; x1 = rotl32(x1, 26); x1 ^= x0;
  x0 += x1; x1 = rotl32(x1,  6); x1 ^= x0;
  x0 += k0; x1 += k1 + 3u;
  x0 += x1; x1 = rotl32(x1, 17); x1 ^= x0;
  x0 += x1; x1 = rotl32(x1, 29); x1 ^= x0;
  x0 += x1; x1 = rotl32(x1, 16); x1 ^= x0;
  x0 += x1; x1 = rotl32(x1, 24); x1 ^= x0;
  x0 += k1; x1 += ks2 + 4u;
  x0 += x1; x1 = rotl32(x1, 13); x1 ^= x0;
  x0 += x1; x1 = rotl32(x1, 15); x1 ^= x0;
  x0 += x1; x1 = rotl32(x1, 26); x1 ^= x0;
  x0 += x1; x1 = rotl32(x1,  6); x1 ^= x0;
  x0 += ks2; x1 += k0 + 5u;
  o0 = x0; o1 = x1;
}

__device__ __forceinline__ unsigned short f2bf(float f) {
  unsigned u = __float_as_uint(f);
  unsigned r = (u + 0x7FFFu + ((u >> 16) & 1u)) >> 16;  // RNE
  return (unsigned short)r;
}
__device__ __forceinline__ float bf2f(unsigned short s) {
  return __uint_as_float(((unsigned)s) << 16);
}

__device__ __forceinline__ int lower_bound_i(const int* __restrict__ a, int n, int v) {
  int lo = 0, hi = n;
  while (lo < hi) { int m = (lo + hi) >> 1; if (a[m] < v) lo = m + 1; else hi = m; }
  return lo;
}

// ---------------- parallel segment-bounds precompute ----------------
__global__ __launch_bounds__(256) void seg_bounds_kernel(
    const int* __restrict__ ab, const int* __restrict__ rb,
    int* __restrict__ bounds) {
  int i = blockIdx.x * 256 + threadIdx.x;
  if (i <= BSZ) bounds[i] = lower_bound_i(ab, NFV, i);
  else if (i <= 2 * BSZ + 1) bounds[i] = lower_bound_i(rb, NRV, i - RBOFF);
}

// ---------------- emb -> bf16 hi/lo (once; rows >= VV zero-padded) ----------------
__global__ __launch_bounds__(256) void convert_emb_kernel(
    const float* __restrict__ emb, unsigned short* __restrict__ ehi,
    unsigned short* __restrict__ elo) {
  size_t i = ((size_t)blockIdx.x * 256 + threadIdx.x) * 4;   // grid exact
  int row = (int)(i >> 8);
  float f[4] = {0.f, 0.f, 0.f, 0.f};
  if (row < VV) {
    float4 v = *reinterpret_cast<const float4*>(&emb[i]);
    f[0] = v.x; f[1] = v.y; f[2] = v.z; f[3] = v.w;
  }
  unsigned short h[4], l[4];
#pragma unroll
  for (int j = 0; j < 4; ++j) {
    h[j] = f2bf(f[j]);
    l[j] = f2bf(f[j] - bf2f(h[j]));
  }
  *reinterpret_cast<uint2*>(&ehi[i]) = *reinterpret_cast<uint2*>(h);
  *reinterpret_cast<uint2*>(&elo[i]) = *reinterpret_cast<uint2*>(l);
}

// ---------------- center (bit-identical) + residue mask bytes ----------------
__global__ __launch_bounds__(256) void mask_kernel(
    const float* __restrict__ pcf, const float* __restrict__ rpos,
    const int* __restrict__ bounds, unsigned char* __restrict__ mask) {
  int lane = threadIdx.x & 63;
  int b = blockIdx.x * 4 + (threadIdx.x >> 6);
  int a0 = bounds[b], a1 = bounds[b + 1];
  int r0 = bounds[RBOFF + b], r1 = bounds[RBOFF + b + 1];

  float cp = 0.f;
  if (lane < 3 && a0 < a1) {
    float nv = pcf[(size_t)a0 * 3 + lane];
    for (int aa = a0; aa < a1; ++aa) {
      float cv = nv;
      if (aa + 1 < a1) nv = pcf[(size_t)(aa + 1) * 3 + lane];
      cp += cv;
    }
  }
  if (lane < 3) cp = cp / fmaxf((float)(a1 - a0), 1.0f);
  float cx = __shfl(cp, 0), cy = __shfl(cp, 1), cz = __shfl(cp, 2);

  for (int r = r0 + lane; r < r1; r += 64) {
    float dx = rpos[(size_t)r * 9 + 3] - cx;
    float dy = rpos[(size_t)r * 9 + 4] - cy;
    float dz = rpos[(size_t)r * 9 + 5] - cz;
    mask[r] = (dx * dx + dy * dy + dz * dz < 36.0f) ? 1 : 0;  // == sqrtf<6
  }
}

// ---------------- segment fusion: pure streaming, 8-row chunks + mask bytes ----------------
__global__ __launch_bounds__(256) void fuse_seg_kernel(
    const float* __restrict__ hcf, const int* __restrict__ wid,
    const float* __restrict__ hres, const unsigned char* __restrict__ mask,
    const float* __restrict__ emb, const int* __restrict__ bounds,
    float* __restrict__ pred_vecs) {
  int lane = threadIdx.x & 63;
  int b = blockIdx.x * 4 + (threadIdx.x >> 6);
  int a0 = bounds[b], a1 = bounds[b + 1];
  int r0 = bounds[RBOFF + b], r1 = bounds[RBOFF + b + 1];
  size_t off = (size_t)lane * 4;

  // node sum: 8 independent row loads in flight per chunk
  float4v acc = 0.f;
  int a = a0;
  for (; a + 8 <= a1; a += 8) {
    float4v v[8];
#pragma unroll
    for (int j = 0; j < 8; ++j)
      v[j] = *reinterpret_cast<const float4v*>(&hcf[(size_t)(a + j) * HD + off]);
    acc += ((v[0] + v[1]) + (v[2] + v[3])) + ((v[4] + v[5]) + (v[6] + v[7]));
  }
  for (; a < a1; ++a)
    acc += *reinterpret_cast<const float4v*>(&hcf[(size_t)a * HD + off]);

  size_t o = (size_t)b * (3 * HD);
  *reinterpret_cast<float4v*>(&pred_vecs[o + off]) = acc;
  float4v mv = *reinterpret_cast<const float4v*>(&emb[(size_t)wid[b] * HD + off]);
  *reinterpret_cast<float4v*>(&pred_vecs[o + HD + off]) = mv;

  // residue sum: 8 row loads + one 8B mask load per chunk
  float4v racc = 0.f;
  int r = r0;
  for (; r < r1 && (r & 7); ++r) {
    float4v v = *reinterpret_cast<const float4v*>(&hres[(size_t)r * HD + off]);
    if (mask[r]) racc += v;
  }
  for (; r + 8 <= r1; r += 8) {
    uint2 mw = *reinterpret_cast<const uint2*>(&mask[r]);   // r%8==0: aligned
    float4v v[8];
#pragma unroll
    for (int j = 0; j < 8; ++j)
      v[j] = *reinterpret_cast<const float4v*>(&hres[(size_t)(r + j) * HD + off]);
    float4v s0 = 0.f, s1 = 0.f, s2 = 0.f, s3 = 0.f;
    if (mw.x & 0x000000FFu) s0 += v[0];
    if (mw.x & 0x0000FF00u) s1 += v[1];
    if (mw.x & 0x00FF0000u) s2 += v[2];
    if (mw.x & 0xFF000000u) s3 += v[3];
    if (mw.y & 0x000000FFu) s0 += v[4];
    if (mw.y & 0x0000FF00u) s1 += v[5];
    if (mw.y & 0x00FF0000u) s2 += v[6];
    if (mw.y & 0xFF000000u) s3 += v[7];
    racc += (s0 + s1) + (s2 + s3);
  }
  for (; r < r1; ++r) {
    float4v v = *reinterpret_cast<const float4v*>(&hres[(size_t)r * HD + off]);
    if (mask[r]) racc += v;
  }
  *reinterpret_cast<float4v*>(&pred_vecs[o + 2 * HD + off]) = racc;
}

// ---------------- f32 tiled GEMM for the two MLP layers ----------------
// SPLIT: write bf16 hi/lo (for MFMA score GEMM) instead of f32 C.
template <bool RELU, bool SPLIT>
__global__ __launch_bounds__(256) void gemm_kernel(
    const float* __restrict__ A, const float* __restrict__ B,
    const float* __restrict__ bias, float* __restrict__ C,
    unsigned short* __restrict__ Chi, unsigned short* __restrict__ Clo,
    int M, int N, int K) {
  __shared__ float As[16][64];
  __shared__ float Bs[16][64];
  int t = threadIdx.x;
  int bm = blockIdx.y * 64, bn = blockIdx.x * 64;
  int tx = t & 15, ty = t >> 4;
  float acc[4][4] = {};

  for (int k0 = 0; k0 < K; k0 += 16) {
    {
      int ar = t >> 2, ak = (t & 3) << 2;
      float4 av = *reinterpret_cast<const float4*>(&A[(size_t)(bm + ar) * K + k0 + ak]);
      As[ak + 0][ar] = av.x; As[ak + 1][ar] = av.y;
      As[ak + 2][ar] = av.z; As[ak + 3][ar] = av.w;
    }
    {
      int bk = t >> 4, bnn = (t & 15) << 2;
      float4 bv = *reinterpret_cast<const float4*>(&B[(size_t)(k0 + bk) * N + bn + bnn]);
      *reinterpret_cast<float4*>(&Bs[bk][bnn]) = bv;
    }
    __syncthreads();
#pragma unroll
    for (int kk = 0; kk < 16; ++kk) {
      float4 a = *reinterpret_cast<const float4*>(&As[kk][ty << 2]);
      float4 b = *reinterpret_cast<const float4*>(&Bs[kk][tx << 2]);
      float av4[4] = {a.x, a.y, a.z, a.w};
      float bv4[4] = {b.x, b.y, b.z, b.w};
#pragma unroll
      for (int i = 0; i < 4; ++i)
#pragma unroll
        for (int j = 0; j < 4; ++j)
          acc[i][j] = fmaf(av4[i], bv4[j], acc[i][j]);
    }
    __syncthreads();
  }

#pragma unroll
  for (int i = 0; i < 4; ++i) {
    int row = bm + (ty << 2) + i;
    if (SPLIT) {
      unsigned short h[4], l[4];
#pragma unroll
      for (int j = 0; j < 4; ++j) {
        float v = acc[i][j] + bias[bn + (tx << 2) + j];
        h[j] = f2bf(v);
        l[j] = f2bf(v - bf2f(h[j]));
      }
      size_t base = (size_t)row * N + bn + (tx << 2);
      *reinterpret_cast<uint2*>(&Chi[base]) = *reinterpret_cast<uint2*>(h);
      *reinterpret_cast<uint2*>(&Clo[base]) = *reinterpret_cast<uint2*>(l);
    } else {
#pragma unroll
      for (int j = 0; j < 4; ++j) {
        int col = bn + (tx << 2) + j;
        float v = acc[i][j] + bias[col];
        if (RELU) v = fmaxf(v, 0.f);
        C[(size_t)row * N + col] = v;
      }
    }
  }
}

// ---------------- MFMA 3-term score GEMM, 128x128 tile, bf16 pre-split ----------------
#define SW(row, col) ((col) ^ (((row) & 7) << 3))

__global__ __launch_bounds__(256, 2) void score_gemm_kernel(
    const unsigned short* __restrict__ Ahg, const unsigned short* __restrict__ Alg,
    const unsigned short* __restrict__ Bhg, const unsigned short* __restrict__ Blg,
    float* __restrict__ C) {
  __shared__ __attribute__((aligned(16))) unsigned short Ah[128 * 64];
  __shared__ __attribute__((aligned(16))) unsigned short Al[128 * 64];
  __shared__ __attribute__((aligned(16))) unsigned short Bh[128 * 64];
  __shared__ __attribute__((aligned(16))) unsigned short Bl[128 * 64];

  int t = threadIdx.x;
  int bm = blockIdx.x * 128;          // x fastest: M-blocks share B-tile in L2
  int bn = blockIdx.y * 128;
  int lane = t & 63, wv = t >> 6;
  int wm = wv >> 1, wn = wv & 1;      // 2x2 wave grid, each wave 64x64
  int lr = lane & 15, lg = lane >> 4;

  float4v acc[4][4] = {};

  int srow = t >> 1, scol = (t & 1) * 32;

  for (int kb = 0; kb < 256; kb += 64) {
#pragma unroll
    for (int j = 0; j < 4; ++j) {
      int c = scol + j * 8;
      int li = srow * 64 + SW(srow, c);
      size_t ga = (size_t)(bm + srow) * 256 + kb + c;
      size_t gb = (size_t)(bn + srow) * 256 + kb + c;
      *reinterpret_cast<short8v*>(&Ah[li]) = *reinterpret_cast<const short8v*>(&Ahg[ga]);
      *reinterpret_cast<short8v*>(&Al[li]) = *reinterpret_cast<const short8v*>(&Alg[ga]);
      *reinterpret_cast<short8v*>(&Bh[li]) = *reinterpret_cast<const short8v*>(&Bhg[gb]);
      *reinterpret_cast<short8v*>(&Bl[li]) = *reinterpret_cast<const short8v*>(&Blg[gb]);
    }
    __syncthreads();

#pragma unroll
    for (int ks = 0; ks < 2; ++ks) {
      int ko = ks * 32 + lg * 8;
      short8v aH[4], aL[4], bH[4], bL[4];
#pragma unroll
      for (int f = 0; f < 4; ++f) {
        int ra = wm * 64 + f * 16 + lr;
        int rb2 = wn * 64 + f * 16 + lr;
        aH[f] = *reinterpret_cast<const short8v*>(&Ah[ra * 64 + SW(ra, ko)]);
        aL[f] = *reinterpret_cast<const short8v*>(&Al[ra * 64 + SW(ra, ko)]);
        bH[f] = *reinterpret_cast<const short8v*>(&Bh[rb2 * 64 + SW(rb2, ko)]);
        bL[f] = *reinterpret_cast<const short8v*>(&Bl[rb2 * 64 + SW(rb2, ko)]);
      }
#pragma unroll
      for (int mf = 0; mf < 4; ++mf)
#pragma unroll
        for (int nf = 0; nf < 4; ++nf) {
          acc[mf][nf] = __builtin_amdgcn_mfma_f32_16x16x32_bf16(
              aH[mf], bH[nf], acc[mf][nf], 0, 0, 0);
          acc[mf][nf] = __builtin_amdgcn_mfma_f32_16x16x32_bf16(
              aH[mf], bL[nf], acc[mf][nf], 0, 0, 0);
          acc[mf][nf] = __builtin_amdgcn_mfma_f32_16x16x32_bf16(
              aL[mf], bH[nf], acc[mf][nf], 0, 0, 0);
        }
    }
    __syncthreads();
  }

  // epilogue: C/D layout col = lane&15, row = (lane>>4)*4 + reg  [m89]
#pragma unroll
  for (int mf = 0; mf < 4; ++mf)
#pragma unroll
    for (int nf = 0; nf < 4; ++nf) {
      int col = bn + wn * 64 + nf * 16 + lr;
      if (col < VV) {
#pragma unroll
        for (int rr = 0; rr < 4; ++rr) {
          int row = bm + wm * 64 + mf * 16 + lg * 4 + rr;
          C[(size_t)row * VV + col] = acc[mf][nf][rr];
        }
      }
    }
}

// ---------------- single-pass top-5 + threefry pick ----------------
#define BETTER(av, ai, bv, bi) ((av) > (bv) || ((av) == (bv) && (ai) < (bi)))

__global__ __launch_bounds__(256) void topk_kernel(
    const float* __restrict__ scores, float* __restrict__ preds,
    unsigned k1a, unsigned k1b, unsigned k2a, unsigned k2b) {
  int lane = threadIdx.x & 63;
  int row = (blockIdx.x << 2) + (threadIdx.x >> 6);
  const float* s = scores + (size_t)row * VV;

  const float NEG = -__builtin_huge_valf();
  float v0 = NEG, v1 = NEG, v2 = NEG, v3 = NEG, v4 = NEG;
  int i0 = 0x7FFFFFFF, i1 = 0x7FFFFFFF, i2 = 0x7FFFFFFF, i3 = 0x7FFFFFFF, i4 = 0x7FFFFFFF;

  for (int v = lane; v < VV; v += 64) {
    float val = s[v];
    if (BETTER(val, v, v4, i4)) {
      if (BETTER(val, v, v3, i3)) {
        v4 = v3; i4 = i3;
        if (BETTER(val, v, v2, i2)) {
          v3 = v2; i3 = i2;
          if (BETTER(val, v, v1, i1)) {
            v2 = v1; i2 = i1;
            if (BETTER(val, v, v0, i0)) {
              v1 = v0; i1 = i0; v0 = val; i0 = v;
            } else { v1 = val; i1 = v; }
          } else { v2 = val; i2 = v; }
        } else { v3 = val; i3 = v; }
      } else { v4 = val; i4 = v; }
    }
  }

  int sel0, sel1, sel2, sel3, sel4;
#pragma unroll
  for (int p = 0; p < TOPKN; ++p) {
    float bv = v0; int bi = i0;
#pragma unroll
    for (int off = 32; off > 0; off >>= 1) {
      float ov = __shfl_xor(bv, off);
      int   oi = __shfl_xor(bi, off);
      if (BETTER(ov, oi, bv, bi)) { bv = ov; bi = oi; }
    }
    if (p == 0) sel0 = bi; else if (p == 1) sel1 = bi; else if (p == 2) sel2 = bi;
    else if (p == 3) sel3 = bi; else sel4 = bi;
    if (bi == i0) {  // owner lane removes its head
      v0 = v1; i0 = i1; v1 = v2; i1 = i2; v2 = v3; i2 = i3; v3 = v4; i3 = i4;
      v4 = NEG; i4 = 0x7FFFFFFF;
    }
  }

  if (lane == 0) {
    unsigned i = (unsigned)row;
    unsigned h0, h1, l0, l1;
    threefry2x32(k1a, k1b, 0u, i, h0, h1);
    threefry2x32(k2a, k2b, 0u, i, l0, l1);
    unsigned hb = h0 ^ h1;
    unsigned lb = l0 ^ l1;
    unsigned idx = ((hb % 5u) + (lb % 5u)) % 5u;
    int pick = (idx == 0) ? sel0 : (idx == 1) ? sel1 : (idx == 2) ? sel2
             : (idx == 3) ? sel3 : sel4;
    preds[row] = (float)pick;
  }
}

extern "C" void kernel_launch(void* const* d_in, const int* in_sizes, int n_in,
                              void* d_out, int out_size, void* d_ws, size_t ws_size,
                              hipStream_t stream) {
  const float* hcf  = (const float*)d_in[0];
  const float* pcf  = (const float*)d_in[1];
  const int*   wid  = (const int*)d_in[2];
  const int*   ab   = (const int*)d_in[3];
  const float* hres = (const float*)d_in[4];
  const float* rpos = (const float*)d_in[5];
  const int*   rb   = (const int*)d_in[6];
  const float* emb  = (const float*)d_in[7];
  const float* w1   = (const float*)d_in[8];
  const float* bb1  = (const float*)d_in[9];
  const float* w2   = (const float*)d_in[10];
  const float* bb2  = (const float*)d_in[11];

  float* out    = (float*)d_out;
  float* scores = out;
  float* preds  = out + (size_t)BSZ * VV;

  float* pred_vecs = out;                          // dead before scores written
  float* hbuf      = out + (size_t)BSZ * 768;      // dead before scores written

  // d_ws layout (all rewritten every call):
  char* ws = (char*)d_ws;
  int*            bounds = (int*)(ws);                      // 32 KB
  unsigned char*  mask   = (unsigned char*)(ws + 0x10000);  // 256 KB
  unsigned short* mh_hi  = (unsigned short*)(ws + 0x100000);  // 2 MB
  unsigned short* mh_lo  = (unsigned short*)(ws + 0x300000);  // 2 MB
  unsigned short* emb_hi = (unsigned short*)(ws + 0x500000);  // 4.03 MB
  unsigned short* emb_lo = (unsigned short*)(ws + 0x900000);  // 4.03 MB

  seg_bounds_kernel<<<(2 * (BSZ + 1) + 255) / 256, 256, 0, stream>>>(ab, rb, bounds);

  convert_emb_kernel<<<(EPAD * 256 / 4) / 256, 256, 0, stream>>>(emb, emb_hi, emb_lo);

  mask_kernel<<<BSZ / 4, 256, 0, stream>>>(pcf, rpos, bounds, mask);

  fuse_seg_kernel<<<BSZ / 4, 256, 0, stream>>>(
      hcf, wid, hres, mask, emb, bounds, pred_vecs);

  gemm_kernel<true, false><<<dim3(256 / 64, BSZ / 64), 256, 0, stream>>>(
      pred_vecs, w1, bb1, hbuf, nullptr, nullptr, BSZ, 256, 768);
  gemm_kernel<false, true><<<dim3(256 / 64, BSZ / 64), 256, 0, stream>>>(
      hbuf, w2, bb2, nullptr, mh_hi, mh_lo, BSZ, 256, 256);

  score_gemm_kernel<<<dim3(BSZ / 128, (VV + 127) / 128), 256, 0, stream>>>(
      mh_hi, mh_lo, emb_hi, emb_lo, scores);

  unsigned k1a, k1b, k2a, k2b;
  threefry2x32(0u, 1u, 0u, 0u, k1a, k1b);
  threefry2x32(0u, 1u, 0u, 1u, k2a, k2b);
  topk_kernel<<<BSZ / 4, 256, 0, stream>>>(scores, preds, k1a, k1b, k2a, k2b);
}

// Round 9
// 295.909 us; speedup vs baseline: 2.6125x; 1.1645x over previous
//
#include <hip/hip_runtime.h>
#include <hip/hip_bf16.h>
#include <cstdint>

#define HD   256
#define BSZ  4096
#define NFV  131072
#define NRV  262144
#define VV   8001
#define TOPKN 5
#define RBOFF (BSZ + 1)
#define EPAD 8064   // emb rows padded to 63*128

typedef __attribute__((ext_vector_type(8))) short short8v;
typedef __attribute__((ext_vector_type(4))) float float4v;

// ---------------- Threefry-2x32 (JAX-exact, 20 rounds) ----------------
__host__ __device__ __forceinline__ unsigned rotl32(unsigned v, int d) {
  return (v << d) | (v >> (32 - d));
}

__host__ __device__ __forceinline__ void threefry2x32(
    unsigned k0, unsigned k1, unsigned x0, unsigned x1,
    unsigned& o0, unsigned& o1) {
  unsigned ks2 = k0 ^ k1 ^ 0x1BD11BDAu;
  x0 += k0; x1 += k1;
  x0 += x1; x1 = rotl32(x1, 13); x1 ^= x0;
  x0 += x1; x1 = rotl32(x1, 15); x1 ^= x0;
  x0 += x1; x1 = rotl32(x1, 26); x1 ^= x0;
  x0 += x1; x1 = rotl32(x1,  6); x1 ^= x0;
  x0 += k1; x1 += ks2 + 1u;
  x0 += x1; x1 = rotl32(x1, 17); x1 ^= x0;
  x0 += x1; x1 = rotl32(x1, 29); x1 ^= x0;
  x0 += x1; x1 = rotl32(x1, 16); x1 ^= x0;
  x0 += x1; x1 = rotl32(x1, 24); x1 ^= x0;
  x0 += ks2; x1 += k0 + 2u;
  x0 += x1; x1 = rotl32(x1, 13); x1 ^= x0;
  x0 += x1; x1 = rotl32(x1, 15); x1 ^= x0;
  x0 += x1; x1 = rotl32(x1, 26); x1 ^= x0;
  x0 += x1; x1 = rotl32(x1,  6); x1 ^= x0;
  x0 += k0; x1 += k1 + 3u;
  x0 += x1; x1 = rotl32(x1, 17); x1 ^= x0;
  x0 += x1; x1 = rotl32(x1, 29); x1 ^= x0;
  x0 += x1; x1 = rotl32(x1, 16); x1 ^= x0;
  x0 += x1; x1 = rotl32(x1, 24); x1 ^= x0;
  x0 += k1; x1 += ks2 + 4u;
  x0 += x1; x1 = rotl32(x1, 13); x1 ^= x0;
  x0 += x1; x1 = rotl32(x1, 15); x1 ^= x0;
  x0 += x1; x1 = rotl32(x1, 26); x1 ^= x0;
  x0 += x1; x1 = rotl32(x1,  6); x1 ^= x0;
  x0 += ks2; x1 += k0 + 5u;
  o0 = x0; o1 = x1;
}

__device__ __forceinline__ unsigned short f2bf(float f) {
  unsigned u = __float_as_uint(f);
  unsigned r = (u + 0x7FFFu + ((u >> 16) & 1u)) >> 16;  // RNE
  return (unsigned short)r;
}
__device__ __forceinline__ float bf2f(unsigned short s) {
  return __uint_as_float(((unsigned)s) << 16);
}

__device__ __forceinline__ int lower_bound_i(const int* __restrict__ a, int n, int v) {
  int lo = 0, hi = n;
  while (lo < hi) { int m = (lo + hi) >> 1; if (a[m] < v) lo = m + 1; else hi = m; }
  return lo;
}

// async global->LDS, 16B per lane (dest must be base + lane*16)
__device__ __forceinline__ void gl16(const unsigned short* g, unsigned short* l) {
  __builtin_amdgcn_global_load_lds(
      (const __attribute__((address_space(1))) unsigned int*)g,
      (__attribute__((address_space(3))) unsigned int*)l, 16, 0, 0);
}

// ---------------- prep: bounds + emb split + w1/w2 transpose+split ----------------
__global__ __launch_bounds__(256) void prep_kernel(
    const int* __restrict__ ab, const int* __restrict__ rb, int* __restrict__ bounds,
    const float* __restrict__ emb, unsigned short* __restrict__ ehi,
    unsigned short* __restrict__ elo,
    const float* __restrict__ w1, unsigned short* __restrict__ w1th,
    unsigned short* __restrict__ w1tl,
    const float* __restrict__ w2, unsigned short* __restrict__ w2th,
    unsigned short* __restrict__ w2tl) {
  int blk = blockIdx.x, t = threadIdx.x;
  if (blk < 33) {
    int i = blk * 256 + t;
    if (i <= BSZ) bounds[i] = lower_bound_i(ab, NFV, i);
    else if (i <= 2 * BSZ + 1) bounds[i] = lower_bound_i(rb, NRV, i - RBOFF);
  } else if (blk < 33 + 2016) {
    size_t i = ((size_t)(blk - 33) * 256 + t) * 4;
    int row = (int)(i >> 8);
    float f[4] = {0.f, 0.f, 0.f, 0.f};
    if (row < VV) {
      float4 v = *reinterpret_cast<const float4*>(&emb[i]);
      f[0] = v.x; f[1] = v.y; f[2] = v.z; f[3] = v.w;
    }
    unsigned short h[4], l[4];
#pragma unroll
    for (int j = 0; j < 4; ++j) {
      h[j] = f2bf(f[j]);
      l[j] = f2bf(f[j] - bf2f(h[j]));
    }
    *reinterpret_cast<uint2*>(&ehi[i]) = *reinterpret_cast<uint2*>(h);
    *reinterpret_cast<uint2*>(&elo[i]) = *reinterpret_cast<uint2*>(l);
  } else if (blk < 33 + 2016 + 768) {
    int i = (blk - 2049) * 256 + t;          // 0..196607
    int n = i / 768, k = i - n * 768;        // w1t[n][k] = w1[k][n]
    float v = w1[k * 256 + n];
    unsigned short h = f2bf(v);
    w1th[i] = h; w1tl[i] = f2bf(v - bf2f(h));
  } else {
    int i = (blk - 2817) * 256 + t;          // 0..65535
    int n = i >> 8, k = i & 255;
    float v = w2[k * 256 + n];
    unsigned short h = f2bf(v);
    w2th[i] = h; w2tl[i] = f2bf(v - bf2f(h));
  }
}

// ---------------- center (bit-identical) + residue mask bytes ----------------
__global__ __launch_bounds__(256) void mask_kernel(
    const float* __restrict__ pcf, const float* __restrict__ rpos,
    const int* __restrict__ bounds, unsigned char* __restrict__ mask) {
  int lane = threadIdx.x & 63;
  int b = blockIdx.x * 4 + (threadIdx.x >> 6);
  int a0 = bounds[b], a1 = bounds[b + 1];
  int r0 = bounds[RBOFF + b], r1 = bounds[RBOFF + b + 1];

  float cp = 0.f;
  if (lane < 3 && a0 < a1) {
    float nv = pcf[(size_t)a0 * 3 + lane];
    for (int aa = a0; aa < a1; ++aa) {
      float cv = nv;
      if (aa + 1 < a1) nv = pcf[(size_t)(aa + 1) * 3 + lane];
      cp += cv;
    }
  }
  if (lane < 3) cp = cp / fmaxf((float)(a1 - a0), 1.0f);
  float cx = __shfl(cp, 0), cy = __shfl(cp, 1), cz = __shfl(cp, 2);

  for (int r = r0 + lane; r < r1; r += 64) {
    float dx = rpos[(size_t)r * 9 + 3] - cx;
    float dy = rpos[(size_t)r * 9 + 4] - cy;
    float dz = rpos[(size_t)r * 9 + 5] - cz;
    mask[r] = (dx * dx + dy * dy + dz * dz < 36.0f) ? 1 : 0;  // == sqrtf<6
  }
}

// ---------------- segment fusion: streaming sums -> bf16 hi/lo pred_vecs ----------------
__global__ __launch_bounds__(256) void fuse_seg_kernel(
    const float* __restrict__ hcf, const int* __restrict__ wid,
    const float* __restrict__ hres, const unsigned char* __restrict__ mask,
    const unsigned short* __restrict__ ehi, const unsigned short* __restrict__ elo,
    const int* __restrict__ bounds,
    unsigned short* __restrict__ pvh, unsigned short* __restrict__ pvl) {
  int lane = threadIdx.x & 63;
  int b = blockIdx.x * 4 + (threadIdx.x >> 6);
  int a0 = bounds[b], a1 = bounds[b + 1];
  int r0 = bounds[RBOFF + b], r1 = bounds[RBOFF + b + 1];
  size_t off = (size_t)lane * 4;

  float4v acc = 0.f;
  int a = a0;
  for (; a + 8 <= a1; a += 8) {
    float4v v[8];
#pragma unroll
    for (int j = 0; j < 8; ++j)
      v[j] = *reinterpret_cast<const float4v*>(&hcf[(size_t)(a + j) * HD + off]);
    acc += ((v[0] + v[1]) + (v[2] + v[3])) + ((v[4] + v[5]) + (v[6] + v[7]));
  }
  for (; a < a1; ++a)
    acc += *reinterpret_cast<const float4v*>(&hcf[(size_t)a * HD + off]);

  float4v racc = 0.f;
  int r = r0;
  for (; r < r1 && (r & 7); ++r) {
    float4v v = *reinterpret_cast<const float4v*>(&hres[(size_t)r * HD + off]);
    if (mask[r]) racc += v;
  }
  for (; r + 8 <= r1; r += 8) {
    uint2 mw = *reinterpret_cast<const uint2*>(&mask[r]);
    float4v v[8];
#pragma unroll
    for (int j = 0; j < 8; ++j)
      v[j] = *reinterpret_cast<const float4v*>(&hres[(size_t)(r + j) * HD + off]);
    float4v s0 = 0.f, s1 = 0.f, s2 = 0.f, s3 = 0.f;
    if (mw.x & 0x000000FFu) s0 += v[0];
    if (mw.x & 0x0000FF00u) s1 += v[1];
    if (mw.x & 0x00FF0000u) s2 += v[2];
    if (mw.x & 0xFF000000u) s3 += v[3];
    if (mw.y & 0x000000FFu) s0 += v[4];
    if (mw.y & 0x0000FF00u) s1 += v[5];
    if (mw.y & 0x00FF0000u) s2 += v[6];
    if (mw.y & 0xFF000000u) s3 += v[7];
    racc += (s0 + s1) + (s2 + s3);
  }
  for (; r < r1; ++r) {
    float4v v = *reinterpret_cast<const float4v*>(&hres[(size_t)r * HD + off]);
    if (mask[r]) racc += v;
  }

  size_t o = (size_t)b * 768;
  {
    unsigned short h[4], l[4];
#pragma unroll
    for (int j = 0; j < 4; ++j) {
      h[j] = f2bf(acc[j]); l[j] = f2bf(acc[j] - bf2f(h[j]));
    }
    *reinterpret_cast<uint2*>(&pvh[o + off]) = *reinterpret_cast<uint2*>(h);
    *reinterpret_cast<uint2*>(&pvl[o + off]) = *reinterpret_cast<uint2*>(l);
  }
  *reinterpret_cast<uint2*>(&pvh[o + 256 + off]) =
      *reinterpret_cast<const uint2*>(&ehi[(size_t)wid[b] * 256 + off]);
  *reinterpret_cast<uint2*>(&pvl[o + 256 + off]) =
      *reinterpret_cast<const uint2*>(&elo[(size_t)wid[b] * 256 + off]);
  {
    unsigned short h[4], l[4];
#pragma unroll
    for (int j = 0; j < 4; ++j) {
      h[j] = f2bf(racc[j]); l[j] = f2bf(racc[j] - bf2f(h[j]));
    }
    *reinterpret_cast<uint2*>(&pvh[o + 512 + off]) = *reinterpret_cast<uint2*>(h);
    *reinterpret_cast<uint2*>(&pvl[o + 512 + off]) = *reinterpret_cast<uint2*>(l);
  }
}

// ---------------- MFMA 3-term MLP GEMM, 64x64 tile; bias(+relu) + split write ----------------
// A: M x K split (hi/lo). B: N x K split (transposed weights). Out: M x N split.
template <bool RELU, int K, int N>
__global__ __launch_bounds__(256) void mlp_gemm_kernel(
    const unsigned short* __restrict__ Ahg, const unsigned short* __restrict__ Alg,
    const unsigned short* __restrict__ Bhg, const unsigned short* __restrict__ Blg,
    const float* __restrict__ bias,
    unsigned short* __restrict__ Chi, unsigned short* __restrict__ Clo) {
  __shared__ __attribute__((aligned(16))) unsigned short Ahs[64][72];
  __shared__ __attribute__((aligned(16))) unsigned short Als[64][72];
  __shared__ __attribute__((aligned(16))) unsigned short Bhs[64][72];
  __shared__ __attribute__((aligned(16))) unsigned short Bls[64][72];

  int t = threadIdx.x;
  int bm = blockIdx.y * 64, bn = blockIdx.x * 64;
  int lane = t & 63, wv = t >> 6;
  int wm = wv >> 1, wn = wv & 1;
  int lr = lane & 15, lg = lane >> 4;
  float4v acc[2][2] = {};

  int srow = t >> 2, sc = (t & 3) * 16;

  for (int kb = 0; kb < K; kb += 64) {
    size_t ga = (size_t)(bm + srow) * K + kb + sc;
    size_t gb = (size_t)(bn + srow) * K + kb + sc;
    *reinterpret_cast<short8v*>(&Ahs[srow][sc]) = *reinterpret_cast<const short8v*>(&Ahg[ga]);
    *reinterpret_cast<short8v*>(&Ahs[srow][sc + 8]) = *reinterpret_cast<const short8v*>(&Ahg[ga + 8]);
    *reinterpret_cast<short8v*>(&Als[srow][sc]) = *reinterpret_cast<const short8v*>(&Alg[ga]);
    *reinterpret_cast<short8v*>(&Als[srow][sc + 8]) = *reinterpret_cast<const short8v*>(&Alg[ga + 8]);
    *reinterpret_cast<short8v*>(&Bhs[srow][sc]) = *reinterpret_cast<const short8v*>(&Bhg[gb]);
    *reinterpret_cast<short8v*>(&Bhs[srow][sc + 8]) = *reinterpret_cast<const short8v*>(&Bhg[gb + 8]);
    *reinterpret_cast<short8v*>(&Bls[srow][sc]) = *reinterpret_cast<const short8v*>(&Blg[gb]);
    *reinterpret_cast<short8v*>(&Bls[srow][sc + 8]) = *reinterpret_cast<const short8v*>(&Blg[gb + 8]);
    __syncthreads();

#pragma unroll
    for (int ks = 0; ks < 2; ++ks) {
      int ko = ks * 32 + lg * 8;
      short8v aH[2], aL[2], bH[2], bL[2];
#pragma unroll
      for (int f = 0; f < 2; ++f) {
        aH[f] = *reinterpret_cast<const short8v*>(&Ahs[wm * 32 + f * 16 + lr][ko]);
        aL[f] = *reinterpret_cast<const short8v*>(&Als[wm * 32 + f * 16 + lr][ko]);
        bH[f] = *reinterpret_cast<const short8v*>(&Bhs[wn * 32 + f * 16 + lr][ko]);
        bL[f] = *reinterpret_cast<const short8v*>(&Bls[wn * 32 + f * 16 + lr][ko]);
      }
#pragma unroll
      for (int mf = 0; mf < 2; ++mf)
#pragma unroll
        for (int nf = 0; nf < 2; ++nf) {
          acc[mf][nf] = __builtin_amdgcn_mfma_f32_16x16x32_bf16(
              aH[mf], bH[nf], acc[mf][nf], 0, 0, 0);
          acc[mf][nf] = __builtin_amdgcn_mfma_f32_16x16x32_bf16(
              aH[mf], bL[nf], acc[mf][nf], 0, 0, 0);
          acc[mf][nf] = __builtin_amdgcn_mfma_f32_16x16x32_bf16(
              aL[mf], bH[nf], acc[mf][nf], 0, 0, 0);
        }
    }
    __syncthreads();
  }

  // C/D layout: col = lane&15, row = (lane>>4)*4 + reg  [m89]
#pragma unroll
  for (int mf = 0; mf < 2; ++mf)
#pragma unroll
    for (int nf = 0; nf < 2; ++nf) {
      int col = bn + wn * 32 + nf * 16 + lr;
      float bv = bias[col];
#pragma unroll
      for (int rr = 0; rr < 4; ++rr) {
        int row = bm + wm * 32 + mf * 16 + lg * 4 + rr;
        float v = acc[mf][nf][rr] + bv;
        if (RELU) v = fmaxf(v, 0.f);
        unsigned short h = f2bf(v);
        Chi[(size_t)row * N + col] = h;
        Clo[(size_t)row * N + col] = f2bf(v - bf2f(h));
      }
    }
}

// ---------------- MFMA 3-term score GEMM, m97-style: global_load_lds + linear LDS ----------------
__global__ __launch_bounds__(256, 2) void score_gemm_kernel(
    const unsigned short* __restrict__ Ahg, const unsigned short* __restrict__ Alg,
    const unsigned short* __restrict__ Bhg, const unsigned short* __restrict__ Blg,
    float* __restrict__ C) {
  __shared__ __attribute__((aligned(16))) unsigned short Ah[128 * 64];
  __shared__ __attribute__((aligned(16))) unsigned short Al[128 * 64];
  __shared__ __attribute__((aligned(16))) unsigned short Bh[128 * 64];
  __shared__ __attribute__((aligned(16))) unsigned short Bl[128 * 64];

  int t = threadIdx.x;
  int bm = blockIdx.x * 128;          // x fastest: M-blocks share B-tile in L2
  int bn = blockIdx.y * 128;
  int lane = t & 63, wv = t >> 6;
  int wm = wv >> 1, wn = wv & 1;      // 2x2 waves, each 64x64
  int lr = lane & 15, lg = lane >> 4;

  float4v acc[4][4] = {};

  int rsub = lane >> 3;               // row within 8-row chunk
  int csub = (lane & 7) * 8;          // short offset within 64-col slice

  for (int kb = 0; kb < 256; kb += 64) {
#pragma unroll
    for (int j = 0; j < 4; ++j) {
      int ch = wv * 4 + j;                       // 16 chunks of 8 rows
      int grow = ch * 8 + rsub;
      size_t goA = (size_t)(bm + grow) * 256 + kb + csub;
      size_t goB = (size_t)(bn + grow) * 256 + kb + csub;
      unsigned lo = ch * 512 + lane * 8;         // = grow*64 + csub (linear)
      gl16(&Ahg[goA], &Ah[lo]);
      gl16(&Alg[goA], &Al[lo]);
      gl16(&Bhg[goB], &Bh[lo]);
      gl16(&Blg[goB], &Bl[lo]);
    }
    __syncthreads();

#pragma unroll
    for (int ks = 0; ks < 2; ++ks) {
      int ko = ks * 32 + lg * 8;
      short8v aH[4], aL[4], bH[4], bL[4];
#pragma unroll
      for (int f = 0; f < 4; ++f) {
        int ra = wm * 64 + f * 16 + lr;
        int rb2 = wn * 64 + f * 16 + lr;
        aH[f] = *reinterpret_cast<const short8v*>(&Ah[ra * 64 + ko]);
        aL[f] = *reinterpret_cast<const short8v*>(&Al[ra * 64 + ko]);
        bH[f] = *reinterpret_cast<const short8v*>(&Bh[rb2 * 64 + ko]);
        bL[f] = *reinterpret_cast<const short8v*>(&Bl[rb2 * 64 + ko]);
      }
#pragma unroll
      for (int mf = 0; mf < 4; ++mf)
#pragma unroll
        for (int nf = 0; nf < 4; ++nf) {
          acc[mf][nf] = __builtin_amdgcn_mfma_f32_16x16x32_bf16(
              aH[mf], bH[nf], acc[mf][nf], 0, 0, 0);
          acc[mf][nf] = __builtin_amdgcn_mfma_f32_16x16x32_bf16(
              aH[mf], bL[nf], acc[mf][nf], 0, 0, 0);
          acc[mf][nf] = __builtin_amdgcn_mfma_f32_16x16x32_bf16(
              aL[mf], bH[nf], acc[mf][nf], 0, 0, 0);
        }
    }
    __syncthreads();
  }

  // C/D layout: col = lane&15, row = (lane>>4)*4 + reg  [m89]
#pragma unroll
  for (int mf = 0; mf < 4; ++mf)
#pragma unroll
    for (int nf = 0; nf < 4; ++nf) {
      int col = bn + wn * 64 + nf * 16 + lr;
      if (col < VV) {
#pragma unroll
        for (int rr = 0; rr < 4; ++rr) {
          int row = bm + wm * 64 + mf * 16 + lg * 4 + rr;
          C[(size_t)row * VV + col] = acc[mf][nf][rr];
        }
      }
    }
}

// ---------------- single-pass top-5 + threefry pick ----------------
#define BETTER(av, ai, bv, bi) ((av) > (bv) || ((av) == (bv) && (ai) < (bi)))

__global__ __launch_bounds__(256) void topk_kernel(
    const float* __restrict__ scores, float* __restrict__ preds,
    unsigned k1a, unsigned k1b, unsigned k2a, unsigned k2b) {
  int lane = threadIdx.x & 63;
  int row = (blockIdx.x << 2) + (threadIdx.x >> 6);
  const float* s = scores + (size_t)row * VV;

  const float NEG = -__builtin_huge_valf();
  float v0 = NEG, v1 = NEG, v2 = NEG, v3 = NEG, v4 = NEG;
  int i0 = 0x7FFFFFFF, i1 = 0x7FFFFFFF, i2 = 0x7FFFFFFF, i3 = 0x7FFFFFFF, i4 = 0x7FFFFFFF;

  for (int v = lane; v < VV; v += 64) {
    float val = s[v];
    if (BETTER(val, v, v4, i4)) {
      if (BETTER(val, v, v3, i3)) {
        v4 = v3; i4 = i3;
        if (BETTER(val, v, v2, i2)) {
          v3 = v2; i3 = i2;
          if (BETTER(val, v, v1, i1)) {
            v2 = v1; i2 = i1;
            if (BETTER(val, v, v0, i0)) {
              v1 = v0; i1 = i0; v0 = val; i0 = v;
            } else { v1 = val; i1 = v; }
          } else { v2 = val; i2 = v; }
        } else { v3 = val; i3 = v; }
      } else { v4 = val; i4 = v; }
    }
  }

  int sel0, sel1, sel2, sel3, sel4;
#pragma unroll
  for (int p = 0; p < TOPKN; ++p) {
    float bv = v0; int bi = i0;
#pragma unroll
    for (int off = 32; off > 0; off >>= 1) {
      float ov = __shfl_xor(bv, off);
      int   oi = __shfl_xor(bi, off);
      if (BETTER(ov, oi, bv, bi)) { bv = ov; bi = oi; }
    }
    if (p == 0) sel0 = bi; else if (p == 1) sel1 = bi; else if (p == 2) sel2 = bi;
    else if (p == 3) sel3 = bi; else sel4 = bi;
    if (bi == i0) {
      v0 = v1; i0 = i1; v1 = v2; i1 = i2; v2 = v3; i2 = i3; v3 = v4; i3 = i4;
      v4 = NEG; i4 = 0x7FFFFFFF;
    }
  }

  if (lane == 0) {
    unsigned i = (unsigned)row;
    unsigned h0, h1, l0, l1;
    threefry2x32(k1a, k1b, 0u, i, h0, h1);
    threefry2x32(k2a, k2b, 0u, i, l0, l1);
    unsigned hb = h0 ^ h1;
    unsigned lb = l0 ^ l1;
    unsigned idx = ((hb % 5u) + (lb % 5u)) % 5u;
    int pick = (idx == 0) ? sel0 : (idx == 1) ? sel1 : (idx == 2) ? sel2
             : (idx == 3) ? sel3 : sel4;
    preds[row] = (float)pick;
  }
}

extern "C" void kernel_launch(void* const* d_in, const int* in_sizes, int n_in,
                              void* d_out, int out_size, void* d_ws, size_t ws_size,
                              hipStream_t stream) {
  const float* hcf  = (const float*)d_in[0];
  const float* pcf  = (const float*)d_in[1];
  const int*   wid  = (const int*)d_in[2];
  const int*   ab   = (const int*)d_in[3];
  const float* hres = (const float*)d_in[4];
  const float* rpos = (const float*)d_in[5];
  const int*   rb   = (const int*)d_in[6];
  const float* emb  = (const float*)d_in[7];
  const float* w1   = (const float*)d_in[8];
  const float* bb1  = (const float*)d_in[9];
  const float* w2   = (const float*)d_in[10];
  const float* bb2  = (const float*)d_in[11];

  float* out    = (float*)d_out;
  float* scores = out;
  float* preds  = out + (size_t)BSZ * VV;

  // Intermediates in d_out's dead region (all consumed before scores written):
  char* ob = (char*)d_out;
  unsigned short* pvh  = (unsigned short*)(ob);               // 6 MB
  unsigned short* pvl  = (unsigned short*)(ob + 0x600000);    // 6 MB
  unsigned short* hh   = (unsigned short*)(ob + 0xC00000);    // 2 MB
  unsigned short* hl   = (unsigned short*)(ob + 0xE00000);    // 2 MB
  unsigned short* w1th = (unsigned short*)(ob + 0x1000000);   // 384 KB
  unsigned short* w1tl = (unsigned short*)(ob + 0x1060000);   // 384 KB
  unsigned short* w2th = (unsigned short*)(ob + 0x10C0000);   // 128 KB
  unsigned short* w2tl = (unsigned short*)(ob + 0x10E0000);   // 128 KB

  // d_ws (same footprint as r8):
  char* ws = (char*)d_ws;
  int*            bounds = (int*)(ws);                        // 32 KB
  unsigned char*  mask   = (unsigned char*)(ws + 0x10000);    // 256 KB
  unsigned short* mh_hi  = (unsigned short*)(ws + 0x100000);  // 2 MB
  unsigned short* mh_lo  = (unsigned short*)(ws + 0x300000);  // 2 MB
  unsigned short* emb_hi = (unsigned short*)(ws + 0x500000);  // 4.03 MB
  unsigned short* emb_lo = (unsigned short*)(ws + 0x900000);  // 4.03 MB

  prep_kernel<<<33 + 2016 + 768 + 256, 256, 0, stream>>>(
      ab, rb, bounds, emb, emb_hi, emb_lo, w1, w1th, w1tl, w2, w2th, w2tl);

  mask_kernel<<<BSZ / 4, 256, 0, stream>>>(pcf, rpos, bounds, mask);

  fuse_seg_kernel<<<BSZ / 4, 256, 0, stream>>>(
      hcf, wid, hres, mask, emb_hi, emb_lo, bounds, pvh, pvl);

  // h = relu(pv @ w1 + b1)   [M=4096, N=256, K=768]
  mlp_gemm_kernel<true, 768, 256><<<dim3(4, 64), 256, 0, stream>>>(
      pvh, pvl, w1th, w1tl, bb1, hh, hl);
  // mh = h @ w2 + b2         [M=4096, N=256, K=256]
  mlp_gemm_kernel<false, 256, 256><<<dim3(4, 64), 256, 0, stream>>>(
      hh, hl, w2th, w2tl, bb2, mh_hi, mh_lo);

  score_gemm_kernel<<<dim3(BSZ / 128, (VV + 127) / 128), 256, 0, stream>>>(
      mh_hi, mh_lo, emb_hi, emb_lo, scores);

  unsigned k1a, k1b, k2a, k2b;
  threefry2x32(0u, 1u, 0u, 0u, k1a, k1b);
  threefry2x32(0u, 1u, 0u, 1u, k2a, k2b);
  topk_kernel<<<BSZ / 4, 256, 0, stream>>>(scores, preds, k1a, k1b, k2a, k2b);
}